// Round 2
// baseline (656.337 us; speedup 1.0000x reference)
//
#include <hip/hip_runtime.h>
#include <math.h>

// GCN 4-layer forward on MI355X.
// N=50000 nodes, E=800000 edges, IN=H=128, OUT=64.
// Strategy: build dst-CSR once (no per-feature atomics), then per layer:
//   layers 1-3: agg(h) -> GEMM(+bias+relu)   [valid since agg(hW)=(agg h)W]
//   layer 4:    GEMM (128->64) -> agg(+bias+sigmoid)  [reference order]

#define FIN 128
#define FH  128
#define FOUT 64

// ---------------- precompute kernels ----------------

__global__ void init_deg_cnt(float* deg, int* cnt, int n) {
    int i = blockIdx.x * 256 + threadIdx.x;
    if (i < n) { deg[i] = 1.0f; cnt[i] = 1; }  // self-loop: weight 1, one entry
}

__global__ void edge_deg(const int* __restrict__ dst, const float* __restrict__ w,
                         float* deg, int* cnt, int e) {
    int i = blockIdx.x * 256 + threadIdx.x;
    if (i < e) {
        int d = dst[i];
        atomicAdd(&deg[d], w[i]);
        atomicAdd(&cnt[d], 1);
    }
}

__global__ void make_dinv(float* deg, int n) {
    int i = blockIdx.x * 256 + threadIdx.x;
    if (i < n) deg[i] = 1.0f / sqrtf(deg[i]);   // deg >= 1 always (self-loop)
}

// 3-pass exclusive scan of cnt[] into rowptr[] (rowptr[0]=0, rowptr[i+1]=incl scan)
__global__ void scan_chunk(const int* __restrict__ cnt, int* __restrict__ rowptr,
                           int* __restrict__ bsums, int n) {
    __shared__ int sd[256];
    int t = threadIdx.x;
    int base = blockIdx.x * 1024;
    int v[4]; int local = 0;
#pragma unroll
    for (int j = 0; j < 4; j++) {
        int idx = base + t * 4 + j;
        v[j] = (idx < n) ? cnt[idx] : 0;
        local += v[j];
    }
    sd[t] = local;
    __syncthreads();
    for (int off = 1; off < 256; off <<= 1) {
        int x = (t >= off) ? sd[t - off] : 0;
        __syncthreads();
        sd[t] += x;
        __syncthreads();
    }
    int run = sd[t] - local;   // exclusive prefix for this thread
#pragma unroll
    for (int j = 0; j < 4; j++) {
        int idx = base + t * 4 + j;
        run += v[j];
        if (idx < n) rowptr[idx + 1] = run;
    }
    if (t == 255) bsums[blockIdx.x] = sd[255];
}

__global__ void scan_tops(int* bsums, int nchunks, int* rowptr) {
    if (threadIdx.x == 0 && blockIdx.x == 0) {
        rowptr[0] = 0;
        for (int i = 1; i < nchunks; i++) bsums[i] += bsums[i - 1];
    }
}

__global__ void scan_add(int* rowptr, const int* __restrict__ bsums, int n) {
    int i = blockIdx.x * 256 + threadIdx.x;
    if (i < n) {
        int c = i >> 10;
        if (c > 0) rowptr[i + 1] += bsums[c - 1];
    }
}

__global__ void fill_csr(const int* __restrict__ src, const int* __restrict__ dst,
                         const float* __restrict__ w, const float* __restrict__ dinv,
                         const int* __restrict__ rowptr, int* fill,
                         int* col, float* val, int n, int e) {
    int i = blockIdx.x * 256 + threadIdx.x;
    if (i < n) {
        // self loop for node i: norm = dinv[i]*1*dinv[i]
        int pos = rowptr[i] + atomicAdd(&fill[i], 1);
        col[pos] = i;
        val[pos] = dinv[i] * dinv[i];
    } else if (i < n + e) {
        int ei = i - n;
        int s = src[ei], d = dst[ei];
        int pos = rowptr[d] + atomicAdd(&fill[d], 1);
        col[pos] = s;
        val[pos] = dinv[s] * w[ei] * dinv[d];
    }
}

// ---------------- aggregation ----------------
// One block per node, F threads (feature-parallel). Coalesced 512B (or 256B)
// gather per in-edge, no atomics. EPI: 0 = none, 2 = bias+sigmoid.
template<int F, int EPI>
__global__ void agg_kernel(const float* __restrict__ h, const int* __restrict__ rowptr,
                           const int* __restrict__ col, const float* __restrict__ val,
                           const float* __restrict__ bias, float* __restrict__ out) {
    int row = blockIdx.x;
    int t = threadIdx.x;
    int e0 = rowptr[row], e1 = rowptr[row + 1];
    float acc = 0.f;
    for (int e = e0; e < e1; e++) {
        int s = col[e];        // uniform across block -> scalarized
        float v = val[e];
        acc = fmaf(v, h[(size_t)s * F + t], acc);
    }
    if (EPI == 2) {
        acc += bias[t];
        acc = 1.0f / (1.0f + __expf(-acc));
    }
    out[(size_t)row * F + t] = acc;
}

// ---------------- dense transform ----------------
// 256 threads, M-tile 64 nodes, K (=128) tiled by 64, X and W staged in LDS.
// Thread (ty,tx): rows ty*4..+3, cols {j4*64 + tx*4 .. +3}. EPI: 1 = bias+relu.
template<int NOUT, int EPI>
__global__ __launch_bounds__(256) void gemm_kernel(const float* __restrict__ A,
                                                   const float* __restrict__ W,
                                                   const float* __restrict__ bias,
                                                   float* __restrict__ out, int nrows) {
    constexpr int NJ = NOUT / 64;      // float4 column-groups per thread (2 or 1)
    constexpr int F4R = NOUT / 4;      // float4 per W row
    constexpr int WPAD = NOUT + 4;
    __shared__ float Xs[64][68];
    __shared__ float Ws[64][WPAD];
    int tid = threadIdx.x;
    int m0 = blockIdx.x * 64;
    int ty = tid >> 4, tx = tid & 15;

    float acc[4][NJ * 4];
#pragma unroll
    for (int i = 0; i < 4; i++)
#pragma unroll
        for (int j = 0; j < NJ * 4; j++) acc[i][j] = 0.f;

    for (int kt = 0; kt < 128; kt += 64) {
        // stage X tile: 64 rows x 64 cols
#pragma unroll
        for (int j = 0; j < 4; j++) {
            int f = tid + 256 * j;       // 1024 float4 total
            int r = f >> 4, c4 = f & 15;
            int gr = m0 + r;
            float4 v = make_float4(0.f, 0.f, 0.f, 0.f);
            if (gr < nrows) v = *(const float4*)&A[(size_t)gr * 128 + kt + c4 * 4];
            *(float4*)&Xs[r][c4 * 4] = v;
        }
        // stage W tile: 64 rows x NOUT cols
#pragma unroll
        for (int j = 0; j < 64 * F4R / 256; j++) {
            int f = tid + 256 * j;
            int r = f / F4R, c4 = f % F4R;
            float4 v = *(const float4*)&W[(size_t)(kt + r) * NOUT + c4 * 4];
            *(float4*)&Ws[r][c4 * 4] = v;
        }
        __syncthreads();

#pragma unroll 4
        for (int k = 0; k < 64; k++) {
            float xv[4];
#pragma unroll
            for (int i = 0; i < 4; i++) xv[i] = Xs[ty * 4 + i][k];
#pragma unroll
            for (int j4 = 0; j4 < NJ; j4++) {
                float4 wv = *(const float4*)&Ws[k][(j4 * 16 + tx) * 4];
#pragma unroll
                for (int i = 0; i < 4; i++) {
                    acc[i][j4 * 4 + 0] = fmaf(xv[i], wv.x, acc[i][j4 * 4 + 0]);
                    acc[i][j4 * 4 + 1] = fmaf(xv[i], wv.y, acc[i][j4 * 4 + 1]);
                    acc[i][j4 * 4 + 2] = fmaf(xv[i], wv.z, acc[i][j4 * 4 + 2]);
                    acc[i][j4 * 4 + 3] = fmaf(xv[i], wv.w, acc[i][j4 * 4 + 3]);
                }
            }
        }
        __syncthreads();
    }

#pragma unroll
    for (int i = 0; i < 4; i++) {
        int gr = m0 + ty * 4 + i;
        if (gr >= nrows) continue;
#pragma unroll
        for (int j4 = 0; j4 < NJ; j4++) {
            int n0 = j4 * 64 + tx * 4;
            float4 v;
            v.x = acc[i][j4 * 4 + 0];
            v.y = acc[i][j4 * 4 + 1];
            v.z = acc[i][j4 * 4 + 2];
            v.w = acc[i][j4 * 4 + 3];
            if (EPI == 1) {
                v.x = fmaxf(v.x + bias[n0 + 0], 0.f);
                v.y = fmaxf(v.y + bias[n0 + 1], 0.f);
                v.z = fmaxf(v.z + bias[n0 + 2], 0.f);
                v.w = fmaxf(v.w + bias[n0 + 3], 0.f);
            }
            *(float4*)&out[(size_t)gr * NOUT + n0] = v;
        }
    }
}

// ---------------- launch ----------------

extern "C" void kernel_launch(void* const* d_in, const int* in_sizes, int n_in,
                              void* d_out, int out_size, void* d_ws, size_t ws_size,
                              hipStream_t stream) {
    const float* x  = (const float*)d_in[0];
    const int*   ei = (const int*)d_in[1];
    const float* ew = (const float*)d_in[2];
    const float* W1 = (const float*)d_in[3];
    const float* b1 = (const float*)d_in[4];
    const float* W2 = (const float*)d_in[5];
    const float* b2 = (const float*)d_in[6];
    const float* W3 = (const float*)d_in[7];
    const float* b3 = (const float*)d_in[8];
    const float* W4 = (const float*)d_in[9];
    const float* b4 = (const float*)d_in[10];

    const int N = in_sizes[0] / FIN;        // 50000
    const int E = in_sizes[1] / 2;          // 800000
    const int M = N + E;                    // CSR entries incl self-loops
    const int* srcI = ei;                   // edge_index[0]
    const int* dstI = ei + E;               // edge_index[1]

    // carve workspace (256B aligned)
    char* p = (char*)d_ws;
    auto alloc = [&](size_t bytes) -> void* {
        void* r = (void*)p;
        p += (bytes + 255) & ~(size_t)255;
        return r;
    };
    float* deg    = (float*)alloc((size_t)N * 4);        // becomes dinv
    int*   cnt    = (int*)  alloc((size_t)N * 4);
    int*   rowptr = (int*)  alloc((size_t)(N + 1) * 4);
    int*   fill   = (int*)  alloc((size_t)N * 4);
    int*   col    = (int*)  alloc((size_t)M * 4);
    float* val    = (float*)alloc((size_t)M * 4);
    int*   bsums  = (int*)  alloc(256 * 4);
    float* B1     = (float*)alloc((size_t)N * 128 * 4);
    float* B2     = (float*)alloc((size_t)N * 128 * 4);

    hipMemsetAsync(fill, 0, (size_t)N * 4, stream);

    int gN = (N + 255) / 256;
    int gE = (E + 255) / 256;
    init_deg_cnt<<<gN, 256, 0, stream>>>(deg, cnt, N);
    edge_deg<<<gE, 256, 0, stream>>>(dstI, ew, deg, cnt, E);
    make_dinv<<<gN, 256, 0, stream>>>(deg, N);

    int nchunks = (N + 1023) / 1024;
    scan_chunk<<<nchunks, 256, 0, stream>>>(cnt, rowptr, bsums, N);
    scan_tops<<<1, 1, 0, stream>>>(bsums, nchunks, rowptr);
    scan_add<<<gN, 256, 0, stream>>>(rowptr, bsums, N);

    fill_csr<<<(N + E + 255) / 256, 256, 0, stream>>>(srcI, dstI, ew, deg, rowptr,
                                                      fill, col, val, N, E);

    int gG = (N + 63) / 64;
    // layer 1: agg(x) -> GEMM W1 + b1 + relu
    agg_kernel<128, 0><<<N, 128, 0, stream>>>(x, rowptr, col, val, nullptr, B1);
    gemm_kernel<128, 1><<<gG, 256, 0, stream>>>(B1, W1, b1, B2, N);
    // layer 2
    agg_kernel<128, 0><<<N, 128, 0, stream>>>(B2, rowptr, col, val, nullptr, B1);
    gemm_kernel<128, 1><<<gG, 256, 0, stream>>>(B1, W2, b2, B2, N);
    // layer 3
    agg_kernel<128, 0><<<N, 128, 0, stream>>>(B2, rowptr, col, val, nullptr, B1);
    gemm_kernel<128, 1><<<gG, 256, 0, stream>>>(B1, W3, b3, B2, N);
    // layer 4: transform 128->64 first, then agg + bias + sigmoid -> out
    gemm_kernel<64, 0><<<gG, 256, 0, stream>>>(B2, W4, nullptr, B1, N);
    agg_kernel<64, 2><<<N, 64, 0, stream>>>(B1, rowptr, col, val, b4, (float*)d_out);
}

// Round 4
// 529.550 us; speedup vs baseline: 1.2394x; 1.2394x over previous
//
#include <hip/hip_runtime.h>
#include <math.h>

// GCN 4-layer forward on MI355X.
// N=50000 nodes, E=800000 edges, IN=H=128, OUT=64.
// Strategy: build dst-CSR once (no per-feature atomics), then per layer:
//   layers 1-3: agg(h) -> GEMM(+bias+relu)   [valid since agg(hW)=(agg h)W]
//   layer 4:    GEMM (128->64) -> agg(+bias+sigmoid)  [reference order]
//
// R2 change: agg edge-loop unrolled x8 with independent accumulators to raise
// per-wave memory-level parallelism (R1 counters: VALUBusy 6%, HBM 30% ->
// latency-bound with ~1 outstanding gather/wave).

#define FIN 128
#define FH  128
#define FOUT 64

// ---------------- precompute kernels ----------------

__global__ void init_deg_cnt(float* deg, int* cnt, int n) {
    int i = blockIdx.x * 256 + threadIdx.x;
    if (i < n) { deg[i] = 1.0f; cnt[i] = 1; }  // self-loop: weight 1, one entry
}

__global__ void edge_deg(const int* __restrict__ dst, const float* __restrict__ w,
                         float* deg, int* cnt, int e) {
    int i = blockIdx.x * 256 + threadIdx.x;
    if (i < e) {
        int d = dst[i];
        atomicAdd(&deg[d], w[i]);
        atomicAdd(&cnt[d], 1);
    }
}

__global__ void make_dinv(float* deg, int n) {
    int i = blockIdx.x * 256 + threadIdx.x;
    if (i < n) deg[i] = 1.0f / sqrtf(deg[i]);   // deg >= 1 always (self-loop)
}

// 3-pass exclusive scan of cnt[] into rowptr[] (rowptr[0]=0, rowptr[i+1]=incl scan)
__global__ void scan_chunk(const int* __restrict__ cnt, int* __restrict__ rowptr,
                           int* __restrict__ bsums, int n) {
    __shared__ int sd[256];
    int t = threadIdx.x;
    int base = blockIdx.x * 1024;
    int v[4]; int local = 0;
#pragma unroll
    for (int j = 0; j < 4; j++) {
        int idx = base + t * 4 + j;
        v[j] = (idx < n) ? cnt[idx] : 0;
        local += v[j];
    }
    sd[t] = local;
    __syncthreads();
    for (int off = 1; off < 256; off <<= 1) {
        int x = (t >= off) ? sd[t - off] : 0;
        __syncthreads();
        sd[t] += x;
        __syncthreads();
    }
    int run = sd[t] - local;   // exclusive prefix for this thread
#pragma unroll
    for (int j = 0; j < 4; j++) {
        int idx = base + t * 4 + j;
        run += v[j];
        if (idx < n) rowptr[idx + 1] = run;
    }
    if (t == 255) bsums[blockIdx.x] = sd[255];
}

__global__ void scan_tops(int* bsums, int nchunks, int* rowptr) {
    if (threadIdx.x == 0 && blockIdx.x == 0) {
        rowptr[0] = 0;
        for (int i = 1; i < nchunks; i++) bsums[i] += bsums[i - 1];
    }
}

__global__ void scan_add(int* rowptr, const int* __restrict__ bsums, int n) {
    int i = blockIdx.x * 256 + threadIdx.x;
    if (i < n) {
        int c = i >> 10;
        if (c > 0) rowptr[i + 1] += bsums[c - 1];
    }
}

__global__ void fill_csr(const int* __restrict__ src, const int* __restrict__ dst,
                         const float* __restrict__ w, const float* __restrict__ dinv,
                         const int* __restrict__ rowptr, int* fill,
                         int* col, float* val, int n, int e) {
    int i = blockIdx.x * 256 + threadIdx.x;
    if (i < n) {
        // self loop for node i: norm = dinv[i]*1*dinv[i]
        int pos = rowptr[i] + atomicAdd(&fill[i], 1);
        col[pos] = i;
        val[pos] = dinv[i] * dinv[i];
    } else if (i < n + e) {
        int ei = i - n;
        int s = src[ei], d = dst[ei];
        int pos = rowptr[d] + atomicAdd(&fill[d], 1);
        col[pos] = s;
        val[pos] = dinv[s] * w[ei] * dinv[d];
    }
}

// ---------------- aggregation ----------------
// One block per node, F threads (feature-parallel). Coalesced gather per
// in-edge, no atomics. Edge loop unrolled x8 with independent accumulators:
// 8 gathers in flight per wave instead of 1 (latency-bound fix, R1 counters).
// EPI: 0 = none, 2 = bias+sigmoid.
template<int F, int EPI>
__global__ void agg_kernel(const float* __restrict__ h, const int* __restrict__ rowptr,
                           const int* __restrict__ col, const float* __restrict__ val,
                           const float* __restrict__ bias, float* __restrict__ out) {
    int row = blockIdx.x;
    int t = threadIdx.x;
    int e0 = rowptr[row], e1 = rowptr[row + 1];
    float a0 = 0.f, a1 = 0.f, a2 = 0.f, a3 = 0.f;
    float a4 = 0.f, a5 = 0.f, a6 = 0.f, a7 = 0.f;
    int e = e0;
    for (; e + 8 <= e1; e += 8) {
        int s0 = col[e+0], s1 = col[e+1], s2 = col[e+2], s3 = col[e+3];
        int s4 = col[e+4], s5 = col[e+5], s6 = col[e+6], s7 = col[e+7];
        float v0 = val[e+0], v1 = val[e+1], v2 = val[e+2], v3 = val[e+3];
        float v4 = val[e+4], v5 = val[e+5], v6 = val[e+6], v7 = val[e+7];
        float h0 = h[(size_t)s0 * F + t];
        float h1 = h[(size_t)s1 * F + t];
        float h2 = h[(size_t)s2 * F + t];
        float h3 = h[(size_t)s3 * F + t];
        float h4 = h[(size_t)s4 * F + t];
        float h5 = h[(size_t)s5 * F + t];
        float h6 = h[(size_t)s6 * F + t];
        float h7 = h[(size_t)s7 * F + t];
        a0 = fmaf(v0, h0, a0); a1 = fmaf(v1, h1, a1);
        a2 = fmaf(v2, h2, a2); a3 = fmaf(v3, h3, a3);
        a4 = fmaf(v4, h4, a4); a5 = fmaf(v5, h5, a5);
        a6 = fmaf(v6, h6, a6); a7 = fmaf(v7, h7, a7);
    }
    if (e + 4 <= e1) {
        int s0 = col[e+0], s1 = col[e+1], s2 = col[e+2], s3 = col[e+3];
        float v0 = val[e+0], v1 = val[e+1], v2 = val[e+2], v3 = val[e+3];
        float h0 = h[(size_t)s0 * F + t];
        float h1 = h[(size_t)s1 * F + t];
        float h2 = h[(size_t)s2 * F + t];
        float h3 = h[(size_t)s3 * F + t];
        a0 = fmaf(v0, h0, a0); a1 = fmaf(v1, h1, a1);
        a2 = fmaf(v2, h2, a2); a3 = fmaf(v3, h3, a3);
        e += 4;
    }
    for (; e < e1; ++e) {
        a0 = fmaf(val[e], h[(size_t)col[e] * F + t], a0);
    }
    float acc = ((a0 + a1) + (a2 + a3)) + ((a4 + a5) + (a6 + a7));
    if (EPI == 2) {
        acc += bias[t];
        acc = 1.0f / (1.0f + __expf(-acc));
    }
    out[(size_t)row * F + t] = acc;
}

// ---------------- dense transform ----------------
// 256 threads, M-tile 64 nodes, K (=128) tiled by 64, X and W staged in LDS.
// Thread (ty,tx): rows ty*4..+3, cols {j4*64 + tx*4 .. +3}. EPI: 1 = bias+relu.
template<int NOUT, int EPI>
__global__ __launch_bounds__(256) void gemm_kernel(const float* __restrict__ A,
                                                   const float* __restrict__ W,
                                                   const float* __restrict__ bias,
                                                   float* __restrict__ out, int nrows) {
    constexpr int NJ = NOUT / 64;      // float4 column-groups per thread (2 or 1)
    constexpr int F4R = NOUT / 4;      // float4 per W row
    constexpr int WPAD = NOUT + 4;
    __shared__ float Xs[64][68];
    __shared__ float Ws[64][WPAD];
    int tid = threadIdx.x;
    int m0 = blockIdx.x * 64;
    int ty = tid >> 4, tx = tid & 15;

    float acc[4][NJ * 4];
#pragma unroll
    for (int i = 0; i < 4; i++)
#pragma unroll
        for (int j = 0; j < NJ * 4; j++) acc[i][j] = 0.f;

    for (int kt = 0; kt < 128; kt += 64) {
        // stage X tile: 64 rows x 64 cols
#pragma unroll
        for (int j = 0; j < 4; j++) {
            int f = tid + 256 * j;       // 1024 float4 total
            int r = f >> 4, c4 = f & 15;
            int gr = m0 + r;
            float4 v = make_float4(0.f, 0.f, 0.f, 0.f);
            if (gr < nrows) v = *(const float4*)&A[(size_t)gr * 128 + kt + c4 * 4];
            *(float4*)&Xs[r][c4 * 4] = v;
        }
        // stage W tile: 64 rows x NOUT cols
#pragma unroll
        for (int j = 0; j < 64 * F4R / 256; j++) {
            int f = tid + 256 * j;
            int r = f / F4R, c4 = f % F4R;
            float4 v = *(const float4*)&W[(size_t)(kt + r) * NOUT + c4 * 4];
            *(float4*)&Ws[r][c4 * 4] = v;
        }
        __syncthreads();

#pragma unroll 4
        for (int k = 0; k < 64; k++) {
            float xv[4];
#pragma unroll
            for (int i = 0; i < 4; i++) xv[i] = Xs[ty * 4 + i][k];
#pragma unroll
            for (int j4 = 0; j4 < NJ; j4++) {
                float4 wv = *(const float4*)&Ws[k][(j4 * 16 + tx) * 4];
#pragma unroll
                for (int i = 0; i < 4; i++) {
                    acc[i][j4 * 4 + 0] = fmaf(xv[i], wv.x, acc[i][j4 * 4 + 0]);
                    acc[i][j4 * 4 + 1] = fmaf(xv[i], wv.y, acc[i][j4 * 4 + 1]);
                    acc[i][j4 * 4 + 2] = fmaf(xv[i], wv.z, acc[i][j4 * 4 + 2]);
                    acc[i][j4 * 4 + 3] = fmaf(xv[i], wv.w, acc[i][j4 * 4 + 3]);
                }
            }
        }
        __syncthreads();
    }

#pragma unroll
    for (int i = 0; i < 4; i++) {
        int gr = m0 + ty * 4 + i;
        if (gr >= nrows) continue;
#pragma unroll
        for (int j4 = 0; j4 < NJ; j4++) {
            int n0 = j4 * 64 + tx * 4;
            float4 v;
            v.x = acc[i][j4 * 4 + 0];
            v.y = acc[i][j4 * 4 + 1];
            v.z = acc[i][j4 * 4 + 2];
            v.w = acc[i][j4 * 4 + 3];
            if (EPI == 1) {
                v.x = fmaxf(v.x + bias[n0 + 0], 0.f);
                v.y = fmaxf(v.y + bias[n0 + 1], 0.f);
                v.z = fmaxf(v.z + bias[n0 + 2], 0.f);
                v.w = fmaxf(v.w + bias[n0 + 3], 0.f);
            }
            *(float4*)&out[(size_t)gr * NOUT + n0] = v;
        }
    }
}

// ---------------- launch ----------------

extern "C" void kernel_launch(void* const* d_in, const int* in_sizes, int n_in,
                              void* d_out, int out_size, void* d_ws, size_t ws_size,
                              hipStream_t stream) {
    const float* x  = (const float*)d_in[0];
    const int*   ei = (const int*)d_in[1];
    const float* ew = (const float*)d_in[2];
    const float* W1 = (const float*)d_in[3];
    const float* b1 = (const float*)d_in[4];
    const float* W2 = (const float*)d_in[5];
    const float* b2 = (const float*)d_in[6];
    const float* W3 = (const float*)d_in[7];
    const float* b3 = (const float*)d_in[8];
    const float* W4 = (const float*)d_in[9];
    const float* b4 = (const float*)d_in[10];

    const int N = in_sizes[0] / FIN;        // 50000
    const int E = in_sizes[1] / 2;          // 800000
    const int M = N + E;                    // CSR entries incl self-loops
    const int* srcI = ei;                   // edge_index[0]
    const int* dstI = ei + E;               // edge_index[1]

    // carve workspace (256B aligned)
    char* p = (char*)d_ws;
    auto alloc = [&](size_t bytes) -> void* {
        void* r = (void*)p;
        p += (bytes + 255) & ~(size_t)255;
        return r;
    };
    float* deg    = (float*)alloc((size_t)N * 4);        // becomes dinv
    int*   cnt    = (int*)  alloc((size_t)N * 4);
    int*   rowptr = (int*)  alloc((size_t)(N + 1) * 4);
    int*   fill   = (int*)  alloc((size_t)N * 4);
    int*   col    = (int*)  alloc((size_t)M * 4);
    float* val    = (float*)alloc((size_t)M * 4);
    int*   bsums  = (int*)  alloc(256 * 4);
    float* B1     = (float*)alloc((size_t)N * 128 * 4);
    float* B2     = (float*)alloc((size_t)N * 128 * 4);

    hipMemsetAsync(fill, 0, (size_t)N * 4, stream);

    int gN = (N + 255) / 256;
    int gE = (E + 255) / 256;
    init_deg_cnt<<<gN, 256, 0, stream>>>(deg, cnt, N);
    edge_deg<<<gE, 256, 0, stream>>>(dstI, ew, deg, cnt, E);
    make_dinv<<<gN, 256, 0, stream>>>(deg, N);

    int nchunks = (N + 1023) / 1024;
    scan_chunk<<<nchunks, 256, 0, stream>>>(cnt, rowptr, bsums, N);
    scan_tops<<<1, 1, 0, stream>>>(bsums, nchunks, rowptr);
    scan_add<<<gN, 256, 0, stream>>>(rowptr, bsums, N);

    fill_csr<<<(N + E + 255) / 256, 256, 0, stream>>>(srcI, dstI, ew, deg, rowptr,
                                                      fill, col, val, N, E);

    int gG = (N + 63) / 64;
    // layer 1: agg(x) -> GEMM W1 + b1 + relu
    agg_kernel<128, 0><<<N, 128, 0, stream>>>(x, rowptr, col, val, nullptr, B1);
    gemm_kernel<128, 1><<<gG, 256, 0, stream>>>(B1, W1, b1, B2, N);
    // layer 2
    agg_kernel<128, 0><<<N, 128, 0, stream>>>(B2, rowptr, col, val, nullptr, B1);
    gemm_kernel<128, 1><<<gG, 256, 0, stream>>>(B1, W2, b2, B2, N);
    // layer 3
    agg_kernel<128, 0><<<N, 128, 0, stream>>>(B2, rowptr, col, val, nullptr, B1);
    gemm_kernel<128, 1><<<gG, 256, 0, stream>>>(B1, W3, b3, B2, N);
    // layer 4: transform 128->64 first, then agg + bias + sigmoid -> out
    gemm_kernel<64, 0><<<gG, 256, 0, stream>>>(B2, W4, nullptr, B1, N);
    agg_kernel<64, 2><<<N, 64, 0, stream>>>(B1, rowptr, col, val, b4, (float*)d_out);
}

// Round 5
// 502.846 us; speedup vs baseline: 1.3052x; 1.0531x over previous
//
#include <hip/hip_runtime.h>
#include <math.h>

// GCN 4-layer forward on MI355X.
// N=50000 nodes, E=800000 edges, IN=H=128, OUT=64.
// R4 counters: edge_deg (1.6M scattered atomics) = top kernel, 75us, VALU 0.3%,
//   HBM 9% -> atomic round-trip latency bound. fill_csr similar (~850K atomics).
// R5 changes:
//   (a) single atomic pass: posr[e]=atomicAdd(&cnt[dst],1); CSR scatter reuses
//       posr (no atomics); deg from CSR row-sum (no atomics); val scaled last.
//   (b) the one atomic pass is fused with layer-1 GEMM x@W1 (independent of
//       CSR) so GEMM compute hides atomic latency. hist blocks first in grid.
//   (c) agg: 4 waves/block, one row per wave; F=128 lanes own float2 (dwordx2
//       gathers, 2x bytes in flight per lane).
// Layer algebra: agg(hW)=(agg h)W. L1: T1=x@W1 -> agg+b1+relu.
// L2/L3: agg -> GEMM+b+relu. L4: GEMM 128->64 -> agg+b4+sigmoid.

#define FIN 128

// ---------------- precompute kernels ----------------

__global__ void init_cnt(int* cnt, int n) {
    int i = blockIdx.x * 256 + threadIdx.x;
    if (i < n) cnt[i] = 1;               // slot 0 reserved for self-loop
}

// 3-pass exclusive scan of cnt[] into rowptr[] (rowptr[0]=0, rowptr[i+1]=incl scan)
__global__ void scan_chunk(const int* __restrict__ cnt, int* __restrict__ rowptr,
                           int* __restrict__ bsums, int n) {
    __shared__ int sd[256];
    int t = threadIdx.x;
    int base = blockIdx.x * 1024;
    int v[4]; int local = 0;
#pragma unroll
    for (int j = 0; j < 4; j++) {
        int idx = base + t * 4 + j;
        v[j] = (idx < n) ? cnt[idx] : 0;
        local += v[j];
    }
    sd[t] = local;
    __syncthreads();
    for (int off = 1; off < 256; off <<= 1) {
        int x = (t >= off) ? sd[t - off] : 0;
        __syncthreads();
        sd[t] += x;
        __syncthreads();
    }
    int run = sd[t] - local;
#pragma unroll
    for (int j = 0; j < 4; j++) {
        int idx = base + t * 4 + j;
        run += v[j];
        if (idx < n) rowptr[idx + 1] = run;
    }
    if (t == 255) bsums[blockIdx.x] = sd[255];
}

__global__ void scan_tops(int* bsums, int nchunks, int* rowptr) {
    if (threadIdx.x == 0 && blockIdx.x == 0) {
        rowptr[0] = 0;
        for (int i = 1; i < nchunks; i++) bsums[i] += bsums[i - 1];
    }
}

__global__ void scan_add(int* rowptr, const int* __restrict__ bsums, int n) {
    int i = blockIdx.x * 256 + threadIdx.x;
    if (i < n) {
        int c = i >> 10;
        if (c > 0) rowptr[i + 1] += bsums[c - 1];
    }
}

// atomic-free CSR fill using saved per-edge slots
__global__ void scatter_csr(const int* __restrict__ src, const int* __restrict__ dst,
                            const float* __restrict__ ew, const unsigned short* __restrict__ posr,
                            const int* __restrict__ rowptr,
                            int* __restrict__ col, float* __restrict__ val, int n, int e) {
    int i = blockIdx.x * 256 + threadIdx.x;
    if (i < n) {
        int p = rowptr[i];
        col[p] = i;
        val[p] = 1.0f;                   // raw self-loop weight
    } else if (i < n + e) {
        int k = i - n;
        int d = dst[k];
        int p = rowptr[d] + (int)posr[k];
        col[p] = src[k];
        val[p] = ew[k];                  // raw weight; scaled later
    }
}

// deg[i] = sum of raw weights in row i (incl self-loop) -> dinv = rsqrt
__global__ void row_dinv(const int* __restrict__ rowptr, const float* __restrict__ val,
                         float* __restrict__ dinv, int n) {
    int i = blockIdx.x * 256 + threadIdx.x;
    if (i < n) {
        int a = rowptr[i], b = rowptr[i + 1];
        float s = 0.f;
        for (int k = a; k < b; k++) s += val[k];
        dinv[i] = rsqrtf(s);             // s >= 1 (self-loop)
    }
}

// val[pos] *= dinv[src]*dinv[dst]; self-loop val = dinv^2
__global__ void scale_val(const int* __restrict__ src, const int* __restrict__ dst,
                          const unsigned short* __restrict__ posr, const int* __restrict__ rowptr,
                          const float* __restrict__ dinv, float* __restrict__ val, int n, int e) {
    int i = blockIdx.x * 256 + threadIdx.x;
    if (i < n) {
        val[rowptr[i]] = dinv[i] * dinv[i];
    } else if (i < n + e) {
        int k = i - n;
        int s = src[k], d = dst[k];
        val[rowptr[d] + (int)posr[k]] *= dinv[s] * dinv[d];
    }
}

// ---------------- dense transform body ----------------
// 256 threads, M-tile 64 rows, K=128 tiled by 64, X and W staged in LDS.
// EPI: 0 = none, 1 = bias+relu.
template<int NOUT, int EPI>
__device__ __forceinline__ void gemm_body(int mblk, const float* __restrict__ A,
                                          const float* __restrict__ W,
                                          const float* __restrict__ bias,
                                          float* __restrict__ out, int nrows) {
    constexpr int NJ = NOUT / 64;
    constexpr int F4R = NOUT / 4;
    constexpr int WPAD = NOUT + 4;
    __shared__ float Xs[64][68];
    __shared__ float Ws[64][WPAD];
    int tid = threadIdx.x;
    int m0 = mblk * 64;
    int ty = tid >> 4, tx = tid & 15;

    float acc[4][NJ * 4];
#pragma unroll
    for (int i = 0; i < 4; i++)
#pragma unroll
        for (int j = 0; j < NJ * 4; j++) acc[i][j] = 0.f;

    for (int kt = 0; kt < 128; kt += 64) {
#pragma unroll
        for (int j = 0; j < 4; j++) {
            int f = tid + 256 * j;
            int r = f >> 4, c4 = f & 15;
            int gr = m0 + r;
            float4 v = make_float4(0.f, 0.f, 0.f, 0.f);
            if (gr < nrows) v = *(const float4*)&A[(size_t)gr * 128 + kt + c4 * 4];
            *(float4*)&Xs[r][c4 * 4] = v;
        }
#pragma unroll
        for (int j = 0; j < 64 * F4R / 256; j++) {
            int f = tid + 256 * j;
            int r = f / F4R, c4 = f % F4R;
            float4 v = *(const float4*)&W[(size_t)(kt + r) * NOUT + c4 * 4];
            *(float4*)&Ws[r][c4 * 4] = v;
        }
        __syncthreads();

#pragma unroll 4
        for (int k = 0; k < 64; k++) {
            float xv[4];
#pragma unroll
            for (int i = 0; i < 4; i++) xv[i] = Xs[ty * 4 + i][k];
#pragma unroll
            for (int j4 = 0; j4 < NJ; j4++) {
                float4 wv = *(const float4*)&Ws[k][(j4 * 16 + tx) * 4];
#pragma unroll
                for (int i = 0; i < 4; i++) {
                    acc[i][j4 * 4 + 0] = fmaf(xv[i], wv.x, acc[i][j4 * 4 + 0]);
                    acc[i][j4 * 4 + 1] = fmaf(xv[i], wv.y, acc[i][j4 * 4 + 1]);
                    acc[i][j4 * 4 + 2] = fmaf(xv[i], wv.z, acc[i][j4 * 4 + 2]);
                    acc[i][j4 * 4 + 3] = fmaf(xv[i], wv.w, acc[i][j4 * 4 + 3]);
                }
            }
        }
        __syncthreads();
    }

#pragma unroll
    for (int i = 0; i < 4; i++) {
        int gr = m0 + ty * 4 + i;
        if (gr >= nrows) continue;
#pragma unroll
        for (int j4 = 0; j4 < NJ; j4++) {
            int n0 = j4 * 64 + tx * 4;
            float4 v;
            v.x = acc[i][j4 * 4 + 0];
            v.y = acc[i][j4 * 4 + 1];
            v.z = acc[i][j4 * 4 + 2];
            v.w = acc[i][j4 * 4 + 3];
            if (EPI == 1) {
                v.x = fmaxf(v.x + bias[n0 + 0], 0.f);
                v.y = fmaxf(v.y + bias[n0 + 1], 0.f);
                v.z = fmaxf(v.z + bias[n0 + 2], 0.f);
                v.w = fmaxf(v.w + bias[n0 + 3], 0.f);
            }
            *(float4*)&out[(size_t)gr * NOUT + n0] = v;
        }
    }
}

template<int NOUT, int EPI>
__global__ __launch_bounds__(256) void gemm_kernel(const float* __restrict__ A,
                                                   const float* __restrict__ W,
                                                   const float* __restrict__ bias,
                                                   float* __restrict__ out, int nrows) {
    gemm_body<NOUT, EPI>(blockIdx.x, A, W, bias, out, nrows);
}

// ---------------- fused: dst-histogram (atomics) + layer-1 GEMM ----------------
#define HIST_BLOCKS 256
__global__ __launch_bounds__(256) void fused_hist_gemm1(const int* __restrict__ dst,
                                                        int* __restrict__ cnt,
                                                        unsigned short* __restrict__ posr, int e,
                                                        const float* __restrict__ x,
                                                        const float* __restrict__ W1,
                                                        float* __restrict__ T1, int nrows) {
    if (blockIdx.x < HIST_BLOCKS) {
        const int stride = HIST_BLOCKS * 256;
        int i = blockIdx.x * 256 + threadIdx.x;
        for (; i + 3 * stride < e; i += 4 * stride) {
            int d0 = dst[i];
            int d1 = dst[i + stride];
            int d2 = dst[i + 2 * stride];
            int d3 = dst[i + 3 * stride];
            int p0 = atomicAdd(&cnt[d0], 1);
            int p1 = atomicAdd(&cnt[d1], 1);
            int p2 = atomicAdd(&cnt[d2], 1);
            int p3 = atomicAdd(&cnt[d3], 1);
            posr[i]              = (unsigned short)p0;
            posr[i + stride]     = (unsigned short)p1;
            posr[i + 2 * stride] = (unsigned short)p2;
            posr[i + 3 * stride] = (unsigned short)p3;
        }
        for (; i < e; i += stride) posr[i] = (unsigned short)atomicAdd(&cnt[dst[i]], 1);
        return;
    }
    gemm_body<128, 0>(blockIdx.x - HIST_BLOCKS, x, W1, nullptr, T1, nrows);
}

// ---------------- aggregation ----------------
// 256-thread block = 4 waves; wave handles one row. F=128: lane owns 2 feats
// (float2 gathers); F=64: lane owns 1 feat. x8 unroll for MLP.
// EPI: 0 none, 1 bias+relu, 2 bias+sigmoid.
template<int F, int EPI>
__global__ __launch_bounds__(256) void agg_kernel(const float* __restrict__ h,
                                                  const int* __restrict__ rowptr,
                                                  const int* __restrict__ col,
                                                  const float* __restrict__ val,
                                                  const float* __restrict__ bias,
                                                  float* __restrict__ out, int n) {
    int wv = threadIdx.x >> 6;
    int lane = threadIdx.x & 63;
    int row = blockIdx.x * 4 + wv;
    if (row >= n) return;
    int e0 = rowptr[row], e1 = rowptr[row + 1];

    if (F == 128) {
        const float* hb = h + 2 * lane;
        float2 a0 = {0.f, 0.f}, a1 = {0.f, 0.f}, a2 = {0.f, 0.f}, a3 = {0.f, 0.f};
        float2 a4 = {0.f, 0.f}, a5 = {0.f, 0.f}, a6 = {0.f, 0.f}, a7 = {0.f, 0.f};
        int e = e0;
        for (; e + 8 <= e1; e += 8) {
            int s0 = col[e+0], s1 = col[e+1], s2 = col[e+2], s3 = col[e+3];
            int s4 = col[e+4], s5 = col[e+5], s6 = col[e+6], s7 = col[e+7];
            float v0 = val[e+0], v1 = val[e+1], v2 = val[e+2], v3 = val[e+3];
            float v4 = val[e+4], v5 = val[e+5], v6 = val[e+6], v7 = val[e+7];
            float2 g0 = *(const float2*)&hb[(size_t)s0 * 128];
            float2 g1 = *(const float2*)&hb[(size_t)s1 * 128];
            float2 g2 = *(const float2*)&hb[(size_t)s2 * 128];
            float2 g3 = *(const float2*)&hb[(size_t)s3 * 128];
            float2 g4 = *(const float2*)&hb[(size_t)s4 * 128];
            float2 g5 = *(const float2*)&hb[(size_t)s5 * 128];
            float2 g6 = *(const float2*)&hb[(size_t)s6 * 128];
            float2 g7 = *(const float2*)&hb[(size_t)s7 * 128];
            a0.x = fmaf(v0, g0.x, a0.x); a0.y = fmaf(v0, g0.y, a0.y);
            a1.x = fmaf(v1, g1.x, a1.x); a1.y = fmaf(v1, g1.y, a1.y);
            a2.x = fmaf(v2, g2.x, a2.x); a2.y = fmaf(v2, g2.y, a2.y);
            a3.x = fmaf(v3, g3.x, a3.x); a3.y = fmaf(v3, g3.y, a3.y);
            a4.x = fmaf(v4, g4.x, a4.x); a4.y = fmaf(v4, g4.y, a4.y);
            a5.x = fmaf(v5, g5.x, a5.x); a5.y = fmaf(v5, g5.y, a5.y);
            a6.x = fmaf(v6, g6.x, a6.x); a6.y = fmaf(v6, g6.y, a6.y);
            a7.x = fmaf(v7, g7.x, a7.x); a7.y = fmaf(v7, g7.y, a7.y);
        }
        if (e + 4 <= e1) {
            int s0 = col[e+0], s1 = col[e+1], s2 = col[e+2], s3 = col[e+3];
            float v0 = val[e+0], v1 = val[e+1], v2 = val[e+2], v3 = val[e+3];
            float2 g0 = *(const float2*)&hb[(size_t)s0 * 128];
            float2 g1 = *(const float2*)&hb[(size_t)s1 * 128];
            float2 g2 = *(const float2*)&hb[(size_t)s2 * 128];
            float2 g3 = *(const float2*)&hb[(size_t)s3 * 128];
            a0.x = fmaf(v0, g0.x, a0.x); a0.y = fmaf(v0, g0.y, a0.y);
            a1.x = fmaf(v1, g1.x, a1.x); a1.y = fmaf(v1, g1.y, a1.y);
            a2.x = fmaf(v2, g2.x, a2.x); a2.y = fmaf(v2, g2.y, a2.y);
            a3.x = fmaf(v3, g3.x, a3.x); a3.y = fmaf(v3, g3.y, a3.y);
            e += 4;
        }
        for (; e < e1; ++e) {
            float v = val[e];
            float2 g = *(const float2*)&hb[(size_t)col[e] * 128];
            a0.x = fmaf(v, g.x, a0.x); a0.y = fmaf(v, g.y, a0.y);
        }
        float2 r;
        r.x = ((a0.x + a1.x) + (a2.x + a3.x)) + ((a4.x + a5.x) + (a6.x + a7.x));
        r.y = ((a0.y + a1.y) + (a2.y + a3.y)) + ((a4.y + a5.y) + (a6.y + a7.y));
        if (EPI == 1) {
            r.x = fmaxf(r.x + bias[2 * lane + 0], 0.f);
            r.y = fmaxf(r.y + bias[2 * lane + 1], 0.f);
        }
        *(float2*)&out[(size_t)row * 128 + 2 * lane] = r;
    } else {
        const float* hb = h + lane;
        float a0 = 0.f, a1 = 0.f, a2 = 0.f, a3 = 0.f;
        float a4 = 0.f, a5 = 0.f, a6 = 0.f, a7 = 0.f;
        int e = e0;
        for (; e + 8 <= e1; e += 8) {
            int s0 = col[e+0], s1 = col[e+1], s2 = col[e+2], s3 = col[e+3];
            int s4 = col[e+4], s5 = col[e+5], s6 = col[e+6], s7 = col[e+7];
            float v0 = val[e+0], v1 = val[e+1], v2 = val[e+2], v3 = val[e+3];
            float v4 = val[e+4], v5 = val[e+5], v6 = val[e+6], v7 = val[e+7];
            float g0 = hb[(size_t)s0 * 64];
            float g1 = hb[(size_t)s1 * 64];
            float g2 = hb[(size_t)s2 * 64];
            float g3 = hb[(size_t)s3 * 64];
            float g4 = hb[(size_t)s4 * 64];
            float g5 = hb[(size_t)s5 * 64];
            float g6 = hb[(size_t)s6 * 64];
            float g7 = hb[(size_t)s7 * 64];
            a0 = fmaf(v0, g0, a0); a1 = fmaf(v1, g1, a1);
            a2 = fmaf(v2, g2, a2); a3 = fmaf(v3, g3, a3);
            a4 = fmaf(v4, g4, a4); a5 = fmaf(v5, g5, a5);
            a6 = fmaf(v6, g6, a6); a7 = fmaf(v7, g7, a7);
        }
        if (e + 4 <= e1) {
            int s0 = col[e+0], s1 = col[e+1], s2 = col[e+2], s3 = col[e+3];
            float v0 = val[e+0], v1 = val[e+1], v2 = val[e+2], v3 = val[e+3];
            a0 = fmaf(v0, hb[(size_t)s0 * 64], a0);
            a1 = fmaf(v1, hb[(size_t)s1 * 64], a1);
            a2 = fmaf(v2, hb[(size_t)s2 * 64], a2);
            a3 = fmaf(v3, hb[(size_t)s3 * 64], a3);
            e += 4;
        }
        for (; e < e1; ++e) a0 = fmaf(val[e], hb[(size_t)col[e] * 64], a0);
        float acc = ((a0 + a1) + (a2 + a3)) + ((a4 + a5) + (a6 + a7));
        if (EPI == 2) {
            acc += bias[lane];
            acc = 1.0f / (1.0f + __expf(-acc));
        }
        out[(size_t)row * 64 + lane] = acc;
    }
}

// ---------------- launch ----------------

extern "C" void kernel_launch(void* const* d_in, const int* in_sizes, int n_in,
                              void* d_out, int out_size, void* d_ws, size_t ws_size,
                              hipStream_t stream) {
    const float* x  = (const float*)d_in[0];
    const int*   ei = (const int*)d_in[1];
    const float* ew = (const float*)d_in[2];
    const float* W1 = (const float*)d_in[3];
    const float* b1 = (const float*)d_in[4];
    const float* W2 = (const float*)d_in[5];
    const float* b2 = (const float*)d_in[6];
    const float* W3 = (const float*)d_in[7];
    const float* b3 = (const float*)d_in[8];
    const float* W4 = (const float*)d_in[9];
    const float* b4 = (const float*)d_in[10];

    const int N = in_sizes[0] / FIN;        // 50000
    const int E = in_sizes[1] / 2;          // 800000
    const int M = N + E;                    // CSR entries incl self-loops
    const int* srcI = ei;                   // edge_index[0]
    const int* dstI = ei + E;               // edge_index[1]

    // carve workspace (256B aligned)
    char* p = (char*)d_ws;
    auto alloc = [&](size_t bytes) -> void* {
        void* r = (void*)p;
        p += (bytes + 255) & ~(size_t)255;
        return r;
    };
    float* dinv   = (float*)alloc((size_t)N * 4);
    int*   cnt    = (int*)  alloc((size_t)N * 4);
    int*   rowptr = (int*)  alloc((size_t)(N + 1) * 4);
    unsigned short* posr = (unsigned short*)alloc((size_t)E * 2);
    int*   col    = (int*)  alloc((size_t)M * 4);
    float* val    = (float*)alloc((size_t)M * 4);
    int*   bsums  = (int*)  alloc(256 * 4);
    float* B1     = (float*)alloc((size_t)N * 128 * 4);
    float* B2     = (float*)alloc((size_t)N * 128 * 4);

    int gN = (N + 255) / 256;
    int gG = (N + 63) / 64;
    int gA = (N + 3) / 4;
    int gM = (N + E + 255) / 256;
    int nchunks = (N + 1023) / 1024;

    // precompute: one atomic pass (fused with layer-1 GEMM), then atomic-free
    init_cnt<<<gN, 256, 0, stream>>>(cnt, N);
    fused_hist_gemm1<<<HIST_BLOCKS + gG, 256, 0, stream>>>(dstI, cnt, posr, E,
                                                           x, W1, B1, N);
    scan_chunk<<<nchunks, 256, 0, stream>>>(cnt, rowptr, bsums, N);
    scan_tops<<<1, 1, 0, stream>>>(bsums, nchunks, rowptr);
    scan_add<<<gN, 256, 0, stream>>>(rowptr, bsums, N);
    scatter_csr<<<gM, 256, 0, stream>>>(srcI, dstI, ew, posr, rowptr, col, val, N, E);
    row_dinv<<<gN, 256, 0, stream>>>(rowptr, val, dinv, N);
    scale_val<<<gM, 256, 0, stream>>>(srcI, dstI, posr, rowptr, dinv, val, N, E);

    // layer 1: T1 = x@W1 already in B1; agg + b1 + relu -> B2
    agg_kernel<128, 1><<<gA, 256, 0, stream>>>(B1, rowptr, col, val, b1, B2, N);
    // layer 2: agg -> GEMM + b2 + relu
    agg_kernel<128, 0><<<gA, 256, 0, stream>>>(B2, rowptr, col, val, nullptr, B1, N);
    gemm_kernel<128, 1><<<gG, 256, 0, stream>>>(B1, W2, b2, B2, N);
    // layer 3
    agg_kernel<128, 0><<<gA, 256, 0, stream>>>(B2, rowptr, col, val, nullptr, B1, N);
    gemm_kernel<128, 1><<<gG, 256, 0, stream>>>(B1, W3, b3, B2, N);
    // layer 4: GEMM 128->64, then agg + b4 + sigmoid -> out
    gemm_kernel<64, 0><<<gG, 256, 0, stream>>>(B2, W4, nullptr, B1, N);
    agg_kernel<64, 2><<<gA, 256, 0, stream>>>(B1, rowptr, col, val, b4, (float*)d_out, N);
}

// Round 8
// 478.796 us; speedup vs baseline: 1.3708x; 1.0502x over previous
//
#include <hip/hip_runtime.h>
#include <hip/hip_bf16.h>
#include <math.h>

// GCN 4-layer forward on MI355X.
// N=50000 nodes, E=800000 edges, IN=H=128, OUT=64.
// R5 counters: fused_hist_gemm1 63us, VALU 18%, Occ 23%, LDS 51KB -> the fp32
//   LDS-tiled GEMM at 3 blocks/CU is the bottleneck, not the atomics.
// R6 changes:
//   (a) all GEMMs -> bf16 MFMA 16x16x32, ZERO LDS / ZERO barriers. Wave owns
//       16 rows x NOUT cols; A-frags in 16 VGPRs (8 contig bf16 along K,
//       row=lane&15, k=(lane>>4)*8+j); B from pre-transposed bf16 Wt[n][k]
//       (L2-resident). C/D: col=lane&15, row=(lane>>4)*4+reg (m89-verified).
//   (b) agg epilogues write bf16 (RNE) -> GEMM inputs; gathers stay fp32.
//   (c) uniform layer order GEMM->agg(+bias+act), algebraically = reference.
// Precompute (from R5, kept): one atomic pass (hist fused with gemm1), then
//   atomic-free CSR scatter / row-sum dinv / val scale.

#define FIN 128
#define HIST_BLOCKS 256

typedef __attribute__((ext_vector_type(8))) short bfrag;   // 8 bf16 = 4 VGPR
typedef __attribute__((ext_vector_type(4))) float f32x4;   // MFMA acc

__device__ __forceinline__ short f2bf(float f) {           // RNE float->bf16
    union { float f; unsigned u; } v; v.f = f;
    unsigned r = v.u + 0x7fff + ((v.u >> 16) & 1);
    return (short)(r >> 16);
}

// ---------------- precompute kernels ----------------

__global__ void init_cnt(int* cnt, int n) {
    int i = blockIdx.x * 256 + threadIdx.x;
    if (i < n) cnt[i] = 1;               // slot 0 reserved for self-loop
}

// transpose+cast W1..W4 (fp32 [k][n]) -> Wt (bf16 [n][k])
__global__ void prep_wt(const float* __restrict__ W1, const float* __restrict__ W2,
                        const float* __restrict__ W3, const float* __restrict__ W4,
                        short* __restrict__ Wt1, short* __restrict__ Wt2,
                        short* __restrict__ Wt3, short* __restrict__ Wt4) {
    int i = blockIdx.x * 256 + threadIdx.x;          // 3*16384 + 8192 elems
    if (i < 3 * 16384) {
        int m = i >> 14, r = i & 16383;
        const float* W = (m == 0) ? W1 : (m == 1) ? W2 : W3;
        short* Wt = (m == 0) ? Wt1 : (m == 1) ? Wt2 : Wt3;
        int n = r >> 7, k = r & 127;
        Wt[r] = f2bf(W[k * 128 + n]);
    } else {
        int r = i - 3 * 16384;                        // W4: [128][64] -> Wt4 [64][128]
        if (r < 8192) {
            int n = r >> 7, k = r & 127;
            Wt4[n * 128 + k] = f2bf(W4[k * 64 + n]);
        }
    }
}

// 3-pass exclusive scan of cnt[] into rowptr[]
__global__ void scan_chunk(const int* __restrict__ cnt, int* __restrict__ rowptr,
                           int* __restrict__ bsums, int n) {
    __shared__ int sd[256];
    int t = threadIdx.x;
    int base = blockIdx.x * 1024;
    int v[4]; int local = 0;
#pragma unroll
    for (int j = 0; j < 4; j++) {
        int idx = base + t * 4 + j;
        v[j] = (idx < n) ? cnt[idx] : 0;
        local += v[j];
    }
    sd[t] = local;
    __syncthreads();
    for (int off = 1; off < 256; off <<= 1) {
        int x = (t >= off) ? sd[t - off] : 0;
        __syncthreads();
        sd[t] += x;
        __syncthreads();
    }
    int run = sd[t] - local;
#pragma unroll
    for (int j = 0; j < 4; j++) {
        int idx = base + t * 4 + j;
        run += v[j];
        if (idx < n) rowptr[idx + 1] = run;
    }
    if (t == 255) bsums[blockIdx.x] = sd[255];
}

__global__ void scan_tops(int* bsums, int nchunks, int* rowptr) {
    if (threadIdx.x == 0 && blockIdx.x == 0) {
        rowptr[0] = 0;
        for (int i = 1; i < nchunks; i++) bsums[i] += bsums[i - 1];
    }
}

__global__ void scan_add(int* rowptr, const int* __restrict__ bsums, int n) {
    int i = blockIdx.x * 256 + threadIdx.x;
    if (i < n) {
        int c = i >> 10;
        if (c > 0) rowptr[i + 1] += bsums[c - 1];
    }
}

// atomic-free CSR fill using saved per-edge slots
__global__ void scatter_csr(const int* __restrict__ src, const int* __restrict__ dst,
                            const float* __restrict__ ew, const unsigned short* __restrict__ posr,
                            const int* __restrict__ rowptr,
                            int* __restrict__ col, float* __restrict__ val, int n, int e) {
    int i = blockIdx.x * 256 + threadIdx.x;
    if (i < n) {
        int p = rowptr[i];
        col[p] = i;
        val[p] = 1.0f;                   // raw self-loop weight
    } else if (i < n + e) {
        int k = i - n;
        int d = dst[k];
        int p = rowptr[d] + (int)posr[k];
        col[p] = src[k];
        val[p] = ew[k];                  // raw weight; scaled later
    }
}

__global__ void row_dinv(const int* __restrict__ rowptr, const float* __restrict__ val,
                         float* __restrict__ dinv, int n) {
    int i = blockIdx.x * 256 + threadIdx.x;
    if (i < n) {
        int a = rowptr[i], b = rowptr[i + 1];
        float s = 0.f;
        for (int k = a; k < b; k++) s += val[k];
        dinv[i] = rsqrtf(s);             // s >= 1 (self-loop)
    }
}

__global__ void scale_val(const int* __restrict__ src, const int* __restrict__ dst,
                          const unsigned short* __restrict__ posr, const int* __restrict__ rowptr,
                          const float* __restrict__ dinv, float* __restrict__ val, int n, int e) {
    int i = blockIdx.x * 256 + threadIdx.x;
    if (i < n) {
        val[rowptr[i]] = dinv[i] * dinv[i];
    } else if (i < n + e) {
        int k = i - n;
        int s = src[k], d = dst[k];
        val[rowptr[d] + (int)posr[k]] *= dinv[s] * dinv[d];
    }
}

// ---------------- MFMA GEMM (bf16 in, fp32 out), no LDS ----------------
// Block = 256 thr = 4 waves; wave owns 16 rows x NOUT cols. K = 128 fixed.
// A: row = lane&15, k = (lane>>4)*8 + j (8 contig bf16 -> 1 dwordx4 load).
// B from Wt[n][k] bf16: col = lane&15, same k slicing.
// D: col = lane&15, row = (lane>>4)*4 + reg.
// EPI: 0 none. AFP32: load A as fp32 and cvt (layer-1 reads x).
template<int NOUT, int EPI, bool AFP32>
__device__ __forceinline__ void mgemm_body(int mblk, const void* Ain,
                                           const short* __restrict__ Wt,
                                           const float* __restrict__ bias,
                                           float* __restrict__ out, int nrows) {
    constexpr int NT = NOUT / 16;
    int l = threadIdx.x & 63;
    int lr = l & 15;
    int kg = l >> 4;
    int m0 = mblk * 64 + (threadIdx.x >> 6) * 16;
    int arow = m0 + lr;
    bool rowok = arow < nrows;

    bfrag a[4];
    if (AFP32) {
        const float* A = (const float*)Ain + (size_t)arow * 128 + kg * 8;
#pragma unroll
        for (int kc = 0; kc < 4; kc++) {
            bfrag t;
            if (rowok) {
                float4 u0 = *(const float4*)(A + kc * 32);
                float4 u1 = *(const float4*)(A + kc * 32 + 4);
                t[0] = f2bf(u0.x); t[1] = f2bf(u0.y); t[2] = f2bf(u0.z); t[3] = f2bf(u0.w);
                t[4] = f2bf(u1.x); t[5] = f2bf(u1.y); t[6] = f2bf(u1.z); t[7] = f2bf(u1.w);
            } else {
#pragma unroll
                for (int j = 0; j < 8; j++) t[j] = 0;
            }
            a[kc] = t;
        }
    } else {
        const short* A = (const short*)Ain + (size_t)arow * 128 + kg * 8;
#pragma unroll
        for (int kc = 0; kc < 4; kc++) {
            if (rowok) {
                a[kc] = *(const bfrag*)(A + kc * 32);
            } else {
#pragma unroll
                for (int j = 0; j < 8; j++) a[kc][j] = 0;
            }
        }
    }

    f32x4 acc[NT];
#pragma unroll
    for (int t = 0; t < NT; t++)
#pragma unroll
        for (int j = 0; j < 4; j++) acc[t][j] = 0.f;

#pragma unroll
    for (int nt = 0; nt < NT; nt++) {
        const short* Wc = Wt + (size_t)(nt * 16 + lr) * 128 + kg * 8;
#pragma unroll
        for (int kc = 0; kc < 4; kc++) {
            bfrag b = *(const bfrag*)(Wc + kc * 32);
            acc[nt] = __builtin_amdgcn_mfma_f32_16x16x32_bf16(a[kc], b, acc[nt], 0, 0, 0);
        }
    }

#pragma unroll
    for (int nt = 0; nt < NT; nt++) {
#pragma unroll
        for (int r = 0; r < 4; r++) {
            int orow = m0 + kg * 4 + r;
            if (orow >= nrows) continue;
            int ocol = nt * 16 + lr;
            float v = acc[nt][r];
            if (EPI == 1) v = fmaxf(v + bias[ocol], 0.f);
            out[(size_t)orow * NOUT + ocol] = v;
        }
    }
}

template<int NOUT, int EPI, bool AFP32>
__global__ __launch_bounds__(256) void mgemm_kernel(const void* __restrict__ Ain,
                                                    const short* __restrict__ Wt,
                                                    const float* __restrict__ bias,
                                                    float* __restrict__ out, int nrows) {
    mgemm_body<NOUT, EPI, AFP32>(blockIdx.x, Ain, Wt, bias, out, nrows);
}

// ---------------- fused: dst-histogram (atomics) + layer-1 MFMA GEMM ----------------
__global__ __launch_bounds__(256) void fused_hist_gemm1(const int* __restrict__ dst,
                                                        int* __restrict__ cnt,
                                                        unsigned short* __restrict__ posr, int e,
                                                        const float* __restrict__ x,
                                                        const short* __restrict__ Wt1,
                                                        float* __restrict__ B, int nrows) {
    if (blockIdx.x < HIST_BLOCKS) {
        const int stride = HIST_BLOCKS * 256;
        int i = blockIdx.x * 256 + threadIdx.x;
        for (; i + 3 * stride < e; i += 4 * stride) {
            int d0 = dst[i];
            int d1 = dst[i + stride];
            int d2 = dst[i + 2 * stride];
            int d3 = dst[i + 3 * stride];
            int p0 = atomicAdd(&cnt[d0], 1);
            int p1 = atomicAdd(&cnt[d1], 1);
            int p2 = atomicAdd(&cnt[d2], 1);
            int p3 = atomicAdd(&cnt[d3], 1);
            posr[i]              = (unsigned short)p0;
            posr[i + stride]     = (unsigned short)p1;
            posr[i + 2 * stride] = (unsigned short)p2;
            posr[i + 3 * stride] = (unsigned short)p3;
        }
        for (; i < e; i += stride) posr[i] = (unsigned short)atomicAdd(&cnt[dst[i]], 1);
        return;
    }
    mgemm_body<128, 0, true>(blockIdx.x - HIST_BLOCKS, x, Wt1, nullptr, B, nrows);
}

// ---------------- aggregation ----------------
// 256-thread block = 4 waves; wave handles one row. F=128: lane owns float2;
// F=64: lane owns 1 feat. x8 edge unroll for MLP. Gathers fp32.
// EPI: 1 bias+relu, 2 bias+sigmoid. OB: 0 fp32 out, 1 bf16 out (feeds MFMA).
template<int F, int EPI, int OB>
__global__ __launch_bounds__(256) void agg_kernel(const float* __restrict__ h,
                                                  const int* __restrict__ rowptr,
                                                  const int* __restrict__ col,
                                                  const float* __restrict__ val,
                                                  const float* __restrict__ bias,
                                                  void* __restrict__ outv, int n) {
    int wv = threadIdx.x >> 6;
    int lane = threadIdx.x & 63;
    int row = blockIdx.x * 4 + wv;
    if (row >= n) return;
    int e0 = rowptr[row], e1 = rowptr[row + 1];

    if (F == 128) {
        const float* hb = h + 2 * lane;
        float2 a0 = {0.f, 0.f}, a1 = {0.f, 0.f}, a2 = {0.f, 0.f}, a3 = {0.f, 0.f};
        float2 a4 = {0.f, 0.f}, a5 = {0.f, 0.f}, a6 = {0.f, 0.f}, a7 = {0.f, 0.f};
        int e = e0;
        for (; e + 8 <= e1; e += 8) {
            int s0 = col[e+0], s1 = col[e+1], s2 = col[e+2], s3 = col[e+3];
            int s4 = col[e+4], s5 = col[e+5], s6 = col[e+6], s7 = col[e+7];
            float v0 = val[e+0], v1 = val[e+1], v2 = val[e+2], v3 = val[e+3];
            float v4 = val[e+4], v5 = val[e+5], v6 = val[e+6], v7 = val[e+7];
            float2 g0 = *(const float2*)&hb[(size_t)s0 * 128];
            float2 g1 = *(const float2*)&hb[(size_t)s1 * 128];
            float2 g2 = *(const float2*)&hb[(size_t)s2 * 128];
            float2 g3 = *(const float2*)&hb[(size_t)s3 * 128];
            float2 g4 = *(const float2*)&hb[(size_t)s4 * 128];
            float2 g5 = *(const float2*)&hb[(size_t)s5 * 128];
            float2 g6 = *(const float2*)&hb[(size_t)s6 * 128];
            float2 g7 = *(const float2*)&hb[(size_t)s7 * 128];
            a0.x = fmaf(v0, g0.x, a0.x); a0.y = fmaf(v0, g0.y, a0.y);
            a1.x = fmaf(v1, g1.x, a1.x); a1.y = fmaf(v1, g1.y, a1.y);
            a2.x = fmaf(v2, g2.x, a2.x); a2.y = fmaf(v2, g2.y, a2.y);
            a3.x = fmaf(v3, g3.x, a3.x); a3.y = fmaf(v3, g3.y, a3.y);
            a4.x = fmaf(v4, g4.x, a4.x); a4.y = fmaf(v4, g4.y, a4.y);
            a5.x = fmaf(v5, g5.x, a5.x); a5.y = fmaf(v5, g5.y, a5.y);
            a6.x = fmaf(v6, g6.x, a6.x); a6.y = fmaf(v6, g6.y, a6.y);
            a7.x = fmaf(v7, g7.x, a7.x); a7.y = fmaf(v7, g7.y, a7.y);
        }
        if (e + 4 <= e1) {
            int s0 = col[e+0], s1 = col[e+1], s2 = col[e+2], s3 = col[e+3];
            float v0 = val[e+0], v1 = val[e+1], v2 = val[e+2], v3 = val[e+3];
            float2 g0 = *(const float2*)&hb[(size_t)s0 * 128];
            float2 g1 = *(const float2*)&hb[(size_t)s1 * 128];
            float2 g2 = *(const float2*)&hb[(size_t)s2 * 128];
            float2 g3 = *(const float2*)&hb[(size_t)s3 * 128];
            a0.x = fmaf(v0, g0.x, a0.x); a0.y = fmaf(v0, g0.y, a0.y);
            a1.x = fmaf(v1, g1.x, a1.x); a1.y = fmaf(v1, g1.y, a1.y);
            a2.x = fmaf(v2, g2.x, a2.x); a2.y = fmaf(v2, g2.y, a2.y);
            a3.x = fmaf(v3, g3.x, a3.x); a3.y = fmaf(v3, g3.y, a3.y);
            e += 4;
        }
        for (; e < e1; ++e) {
            float v = val[e];
            float2 g = *(const float2*)&hb[(size_t)col[e] * 128];
            a0.x = fmaf(v, g.x, a0.x); a0.y = fmaf(v, g.y, a0.y);
        }
        float2 r;
        r.x = ((a0.x + a1.x) + (a2.x + a3.x)) + ((a4.x + a5.x) + (a6.x + a7.x));
        r.y = ((a0.y + a1.y) + (a2.y + a3.y)) + ((a4.y + a5.y) + (a6.y + a7.y));
        if (EPI == 1) {
            r.x = fmaxf(r.x + bias[2 * lane + 0], 0.f);
            r.y = fmaxf(r.y + bias[2 * lane + 1], 0.f);
        }
        if (OB == 1) {
            unsigned pk = (unsigned)(unsigned short)f2bf(r.x)
                        | ((unsigned)(unsigned short)f2bf(r.y) << 16);
            ((unsigned*)outv)[(size_t)row * 64 + lane] = pk;
        } else {
            *(float2*)&((float*)outv)[(size_t)row * 128 + 2 * lane] = r;
        }
    } else {
        const float* hb = h + lane;
        float a0 = 0.f, a1 = 0.f, a2 = 0.f, a3 = 0.f;
        float a4 = 0.f, a5 = 0.f, a6 = 0.f, a7 = 0.f;
        int e = e0;
        for (; e + 8 <= e1; e += 8) {
            int s0 = col[e+0], s1 = col[e+1], s2 = col[e+2], s3 = col[e+3];
            int s4 = col[e+4], s5 = col[e+5], s6 = col[e+6], s7 = col[e+7];
            float v0 = val[e+0], v1 = val[e+1], v2 = val[e+2], v3 = val[e+3];
            float v4 = val[e+4], v5 = val[e+5], v6 = val[e+6], v7 = val[e+7];
            float g0 = hb[(size_t)s0 * 64];
            float g1 = hb[(size_t)s1 * 64];
            float g2 = hb[(size_t)s2 * 64];
            float g3 = hb[(size_t)s3 * 64];
            float g4 = hb[(size_t)s4 * 64];
            float g5 = hb[(size_t)s5 * 64];
            float g6 = hb[(size_t)s6 * 64];
            float g7 = hb[(size_t)s7 * 64];
            a0 = fmaf(v0, g0, a0); a1 = fmaf(v1, g1, a1);
            a2 = fmaf(v2, g2, a2); a3 = fmaf(v3, g3, a3);
            a4 = fmaf(v4, g4, a4); a5 = fmaf(v5, g5, a5);
            a6 = fmaf(v6, g6, a6); a7 = fmaf(v7, g7, a7);
        }
        if (e + 4 <= e1) {
            int s0 = col[e+0], s1 = col[e+1], s2 = col[e+2], s3 = col[e+3];
            float v0 = val[e+0], v1 = val[e+1], v2 = val[e+2], v3 = val[e+3];
            a0 = fmaf(v0, hb[(size_t)s0 * 64], a0);
            a1 = fmaf(v1, hb[(size_t)s1 * 64], a1);
            a2 = fmaf(v2, hb[(size_t)s2 * 64], a2);
            a3 = fmaf(v3, hb[(size_t)s3 * 64], a3);
            e += 4;
        }
        for (; e < e1; ++e) a0 = fmaf(val[e], hb[(size_t)col[e] * 64], a0);
        float acc = ((a0 + a1) + (a2 + a3)) + ((a4 + a5) + (a6 + a7));
        if (EPI == 2) {
            acc += bias[lane];
            acc = 1.0f / (1.0f + __expf(-acc));
        }
        ((float*)outv)[(size_t)row * 64 + lane] = acc;
    }
}

// ---------------- launch ----------------

extern "C" void kernel_launch(void* const* d_in, const int* in_sizes, int n_in,
                              void* d_out, int out_size, void* d_ws, size_t ws_size,
                              hipStream_t stream) {
    const float* x  = (const float*)d_in[0];
    const int*   ei = (const int*)d_in[1];
    const float* ew = (const float*)d_in[2];
    const float* W1 = (const float*)d_in[3];
    const float* b1 = (const float*)d_in[4];
    const float* W2 = (const float*)d_in[5];
    const float* b2 = (const float*)d_in[6];
    const float* W3 = (const float*)d_in[7];
    const float* b3 = (const float*)d_in[8];
    const float* W4 = (const float*)d_in[9];
    const float* b4 = (const float*)d_in[10];

    const int N = in_sizes[0] / FIN;        // 50000
    const int E = in_sizes[1] / 2;          // 800000
    const int M = N + E;                    // CSR entries incl self-loops
    const int* srcI = ei;                   // edge_index[0]
    const int* dstI = ei + E;               // edge_index[1]

    // carve workspace (256B aligned)
    char* p = (char*)d_ws;
    auto alloc = [&](size_t bytes) -> void* {
        void* r = (void*)p;
        p += (bytes + 255) & ~(size_t)255;
        return r;
    };
    float* dinv   = (float*)alloc((size_t)N * 4);
    int*   cnt    = (int*)  alloc((size_t)N * 4);
    int*   rowptr = (int*)  alloc((size_t)(N + 1) * 4);
    unsigned short* posr = (unsigned short*)alloc((size_t)E * 2);
    int*   col    = (int*)  alloc((size_t)M * 4);
    float* val    = (float*)alloc((size_t)M * 4);
    int*   bsums  = (int*)  alloc(256 * 4);
    float* B      = (float*)alloc((size_t)N * 128 * 4);   // GEMM outputs (fp32)
    short* G      = (short*)alloc((size_t)N * 128 * 2);   // agg outputs (bf16)
    short* Wt1    = (short*)alloc(16384 * 2);
    short* Wt2    = (short*)alloc(16384 * 2);
    short* Wt3    = (short*)alloc(16384 * 2);
    short* Wt4    = (short*)alloc(8192 * 2);

    int gN = (N + 255) / 256;
    int gG = (N + 63) / 64;
    int gA = (N + 3) / 4;
    int gM = (N + E + 255) / 256;
    int nchunks = (N + 1023) / 1024;

    init_cnt<<<gN, 256, 0, stream>>>(cnt, N);
    prep_wt<<<224, 256, 0, stream>>>(W1, W2, W3, W4, Wt1, Wt2, Wt3, Wt4);
    // one atomic pass (hist) fused with layer-1 MFMA GEMM B = x@W1
    fused_hist_gemm1<<<HIST_BLOCKS + gG, 256, 0, stream>>>(dstI, cnt, posr, E,
                                                           x, Wt1, B, N);
    scan_chunk<<<nchunks, 256, 0, stream>>>(cnt, rowptr, bsums, N);
    scan_tops<<<1, 1, 0, stream>>>(bsums, nchunks, rowptr);
    scan_add<<<gN, 256, 0, stream>>>(rowptr, bsums, N);
    scatter_csr<<<gM, 256, 0, stream>>>(srcI, dstI, ew, posr, rowptr, col, val, N, E);
    row_dinv<<<gN, 256, 0, stream>>>(rowptr, val, dinv, N);
    scale_val<<<gM, 256, 0, stream>>>(srcI, dstI, posr, rowptr, dinv, val, N, E);

    // L1: B = x@W1 (done); A1 = relu(agg(B)+b1) -> G (bf16)
    agg_kernel<128, 1, 1><<<gA, 256, 0, stream>>>(B, rowptr, col, val, b1, G, N);
    // L2: B = G@W2 ; A2 = relu(agg(B)+b2) -> G
    mgemm_kernel<128, 0, false><<<gG, 256, 0, stream>>>(G, Wt2, nullptr, B, N);
    agg_kernel<128, 1, 1><<<gA, 256, 0, stream>>>(B, rowptr, col, val, b2, G, N);
    // L3
    mgemm_kernel<128, 0, false><<<gG, 256, 0, stream>>>(G, Wt3, nullptr, B, N);
    agg_kernel<128, 1, 1><<<gA, 256, 0, stream>>>(B, rowptr, col, val, b3, G, N);
    // L4: B = G@W4 (64 cols); out = sigmoid(agg(B)+b4)
    mgemm_kernel<64, 0, false><<<gG, 256, 0, stream>>>(G, Wt4, nullptr, B, N);
    agg_kernel<64, 2, 0><<<gA, 256, 0, stream>>>(B, rowptr, col, val, b4, d_out, N);
}

// Round 9
// 418.505 us; speedup vs baseline: 1.5683x; 1.1441x over previous
//
#include <hip/hip_runtime.h>
#include <hip/hip_bf16.h>
#include <math.h>

// GCN 4-layer forward on MI355X.
// N=50000 nodes, E=800000 edges, IN=H=128, OUT=64.
// R8 counters: top-5 all agg128 @58.5us, FETCH 187MB, 3.5TB/s eff, VALU 25%,
//   Occ 60% -> agg is HBM/L3-byte-bound on the fp32 gather stream.
// R9 change (single lever): GEMM outputs (agg inputs) -> bf16. Halves gather
//   bytes (435->218MB logical, FETCH ~187->~100MB) and mgemm write traffic.
//   agg gathers ushort/dword + cvt. Adds one RNE rounding per agg input
//   (predicted absmax 0.0039 -> <=0.009, threshold 0.0109).
// Pipeline: one atomic pass (hist fused w/ gemm1) -> atomic-free CSR ->
//   per layer: MFMA GEMM (bf16 in/out, no LDS) -> agg(+bias+act).

#define FIN 128
#define HIST_BLOCKS 256

typedef __attribute__((ext_vector_type(8))) short bfrag;   // 8 bf16 = 4 VGPR
typedef __attribute__((ext_vector_type(4))) float f32x4;   // MFMA acc

__device__ __forceinline__ short f2bf(float f) {           // RNE float->bf16
    union { float f; unsigned u; } v; v.f = f;
    unsigned r = v.u + 0x7fff + ((v.u >> 16) & 1);
    return (short)(r >> 16);
}
__device__ __forceinline__ float bflo(unsigned u) {        // low bf16 -> f32
    union { unsigned x; float f; } c; c.x = u << 16; return c.f;
}
__device__ __forceinline__ float bfhi(unsigned u) {        // high bf16 -> f32
    union { unsigned x; float f; } c; c.x = u & 0xffff0000u; return c.f;
}
__device__ __forceinline__ float bf1(unsigned short u) {
    union { unsigned x; float f; } c; c.x = (unsigned)u << 16; return c.f;
}

// ---------------- precompute kernels ----------------

__global__ void init_cnt(int* cnt, int n) {
    int i = blockIdx.x * 256 + threadIdx.x;
    if (i < n) cnt[i] = 1;               // slot 0 reserved for self-loop
}

// transpose+cast W1..W4 (fp32 [k][n]) -> Wt (bf16 [n][k])
__global__ void prep_wt(const float* __restrict__ W1, const float* __restrict__ W2,
                        const float* __restrict__ W3, const float* __restrict__ W4,
                        short* __restrict__ Wt1, short* __restrict__ Wt2,
                        short* __restrict__ Wt3, short* __restrict__ Wt4) {
    int i = blockIdx.x * 256 + threadIdx.x;          // 3*16384 + 8192 elems
    if (i < 3 * 16384) {
        int m = i >> 14, r = i & 16383;
        const float* W = (m == 0) ? W1 : (m == 1) ? W2 : W3;
        short* Wt = (m == 0) ? Wt1 : (m == 1) ? Wt2 : Wt3;
        int n = r >> 7, k = r & 127;
        Wt[r] = f2bf(W[k * 128 + n]);
    } else {
        int r = i - 3 * 16384;                        // W4: [128][64] -> Wt4 [64][128]
        if (r < 8192) {
            int n = r >> 7, k = r & 127;
            Wt4[n * 128 + k] = f2bf(W4[k * 64 + n]);
        }
    }
}

// 3-pass exclusive scan of cnt[] into rowptr[]
__global__ void scan_chunk(const int* __restrict__ cnt, int* __restrict__ rowptr,
                           int* __restrict__ bsums, int n) {
    __shared__ int sd[256];
    int t = threadIdx.x;
    int base = blockIdx.x * 1024;
    int v[4]; int local = 0;
#pragma unroll
    for (int j = 0; j < 4; j++) {
        int idx = base + t * 4 + j;
        v[j] = (idx < n) ? cnt[idx] : 0;
        local += v[j];
    }
    sd[t] = local;
    __syncthreads();
    for (int off = 1; off < 256; off <<= 1) {
        int x = (t >= off) ? sd[t - off] : 0;
        __syncthreads();
        sd[t] += x;
        __syncthreads();
    }
    int run = sd[t] - local;
#pragma unroll
    for (int j = 0; j < 4; j++) {
        int idx = base + t * 4 + j;
        run += v[j];
        if (idx < n) rowptr[idx + 1] = run;
    }
    if (t == 255) bsums[blockIdx.x] = sd[255];
}

__global__ void scan_tops(int* bsums, int nchunks, int* rowptr) {
    if (threadIdx.x == 0 && blockIdx.x == 0) {
        rowptr[0] = 0;
        for (int i = 1; i < nchunks; i++) bsums[i] += bsums[i - 1];
    }
}

__global__ void scan_add(int* rowptr, const int* __restrict__ bsums, int n) {
    int i = blockIdx.x * 256 + threadIdx.x;
    if (i < n) {
        int c = i >> 10;
        if (c > 0) rowptr[i + 1] += bsums[c - 1];
    }
}

// atomic-free CSR fill using saved per-edge slots
__global__ void scatter_csr(const int* __restrict__ src, const int* __restrict__ dst,
                            const float* __restrict__ ew, const unsigned short* __restrict__ posr,
                            const int* __restrict__ rowptr,
                            int* __restrict__ col, float* __restrict__ val, int n, int e) {
    int i = blockIdx.x * 256 + threadIdx.x;
    if (i < n) {
        int p = rowptr[i];
        col[p] = i;
        val[p] = 1.0f;                   // raw self-loop weight
    } else if (i < n + e) {
        int k = i - n;
        int d = dst[k];
        int p = rowptr[d] + (int)posr[k];
        col[p] = src[k];
        val[p] = ew[k];                  // raw weight; scaled later
    }
}

__global__ void row_dinv(const int* __restrict__ rowptr, const float* __restrict__ val,
                         float* __restrict__ dinv, int n) {
    int i = blockIdx.x * 256 + threadIdx.x;
    if (i < n) {
        int a = rowptr[i], b = rowptr[i + 1];
        float s = 0.f;
        for (int k = a; k < b; k++) s += val[k];
        dinv[i] = rsqrtf(s);             // s >= 1 (self-loop)
    }
}

__global__ void scale_val(const int* __restrict__ src, const int* __restrict__ dst,
                          const unsigned short* __restrict__ posr, const int* __restrict__ rowptr,
                          const float* __restrict__ dinv, float* __restrict__ val, int n, int e) {
    int i = blockIdx.x * 256 + threadIdx.x;
    if (i < n) {
        val[rowptr[i]] = dinv[i] * dinv[i];
    } else if (i < n + e) {
        int k = i - n;
        int s = src[k], d = dst[k];
        val[rowptr[d] + (int)posr[k]] *= dinv[s] * dinv[d];
    }
}

// ---------------- MFMA GEMM (bf16 in, bf16 out), no LDS ----------------
// Block = 256 thr = 4 waves; wave owns 16 rows x NOUT cols. K = 128 fixed.
// A: row = lane&15, k = (lane>>4)*8 + j. B from Wt[n][k] bf16.
// D: col = lane&15, row = (lane>>4)*4 + reg.
// AFP32: load A as fp32 and cvt (layer-1 reads x).
template<int NOUT, bool AFP32>
__device__ __forceinline__ void mgemm_body(int mblk, const void* Ain,
                                           const short* __restrict__ Wt,
                                           short* __restrict__ out, int nrows) {
    constexpr int NT = NOUT / 16;
    int l = threadIdx.x & 63;
    int lr = l & 15;
    int kg = l >> 4;
    int m0 = mblk * 64 + (threadIdx.x >> 6) * 16;
    int arow = m0 + lr;
    bool rowok = arow < nrows;

    bfrag a[4];
    if (AFP32) {
        const float* A = (const float*)Ain + (size_t)arow * 128 + kg * 8;
#pragma unroll
        for (int kc = 0; kc < 4; kc++) {
            bfrag t;
            if (rowok) {
                float4 u0 = *(const float4*)(A + kc * 32);
                float4 u1 = *(const float4*)(A + kc * 32 + 4);
                t[0] = f2bf(u0.x); t[1] = f2bf(u0.y); t[2] = f2bf(u0.z); t[3] = f2bf(u0.w);
                t[4] = f2bf(u1.x); t[5] = f2bf(u1.y); t[6] = f2bf(u1.z); t[7] = f2bf(u1.w);
            } else {
#pragma unroll
                for (int j = 0; j < 8; j++) t[j] = 0;
            }
            a[kc] = t;
        }
    } else {
        const short* A = (const short*)Ain + (size_t)arow * 128 + kg * 8;
#pragma unroll
        for (int kc = 0; kc < 4; kc++) {
            if (rowok) {
                a[kc] = *(const bfrag*)(A + kc * 32);
            } else {
#pragma unroll
                for (int j = 0; j < 8; j++) a[kc][j] = 0;
            }
        }
    }

    f32x4 acc[NT];
#pragma unroll
    for (int t = 0; t < NT; t++)
#pragma unroll
        for (int j = 0; j < 4; j++) acc[t][j] = 0.f;

#pragma unroll
    for (int nt = 0; nt < NT; nt++) {
        const short* Wc = Wt + (size_t)(nt * 16 + lr) * 128 + kg * 8;
#pragma unroll
        for (int kc = 0; kc < 4; kc++) {
            bfrag b = *(const bfrag*)(Wc + kc * 32);
            acc[nt] = __builtin_amdgcn_mfma_f32_16x16x32_bf16(a[kc], b, acc[nt], 0, 0, 0);
        }
    }

#pragma unroll
    for (int nt = 0; nt < NT; nt++) {
#pragma unroll
        for (int r = 0; r < 4; r++) {
            int orow = m0 + kg * 4 + r;
            if (orow >= nrows) continue;
            int ocol = nt * 16 + lr;
            out[(size_t)orow * NOUT + ocol] = f2bf(acc[nt][r]);
        }
    }
}

template<int NOUT, bool AFP32>
__global__ __launch_bounds__(256) void mgemm_kernel(const void* __restrict__ Ain,
                                                    const short* __restrict__ Wt,
                                                    short* __restrict__ out, int nrows) {
    mgemm_body<NOUT, AFP32>(blockIdx.x, Ain, Wt, out, nrows);
}

// ---------------- fused: dst-histogram (atomics) + layer-1 MFMA GEMM ----------------
__global__ __launch_bounds__(256) void fused_hist_gemm1(const int* __restrict__ dst,
                                                        int* __restrict__ cnt,
                                                        unsigned short* __restrict__ posr, int e,
                                                        const float* __restrict__ x,
                                                        const short* __restrict__ Wt1,
                                                        short* __restrict__ B, int nrows) {
    if (blockIdx.x < HIST_BLOCKS) {
        const int stride = HIST_BLOCKS * 256;
        int i = blockIdx.x * 256 + threadIdx.x;
        for (; i + 3 * stride < e; i += 4 * stride) {
            int d0 = dst[i];
            int d1 = dst[i + stride];
            int d2 = dst[i + 2 * stride];
            int d3 = dst[i + 3 * stride];
            int p0 = atomicAdd(&cnt[d0], 1);
            int p1 = atomicAdd(&cnt[d1], 1);
            int p2 = atomicAdd(&cnt[d2], 1);
            int p3 = atomicAdd(&cnt[d3], 1);
            posr[i]              = (unsigned short)p0;
            posr[i + stride]     = (unsigned short)p1;
            posr[i + 2 * stride] = (unsigned short)p2;
            posr[i + 3 * stride] = (unsigned short)p3;
        }
        for (; i < e; i += stride) posr[i] = (unsigned short)atomicAdd(&cnt[dst[i]], 1);
        return;
    }
    mgemm_body<128, true>(blockIdx.x - HIST_BLOCKS, x, Wt1, B, nrows);
}

// ---------------- aggregation (bf16 gathers) ----------------
// 256-thread block = 4 waves; wave handles one row. F=128: lane owns 2 feats
// (one dword = 2 bf16 per gather); F=64: lane owns 1 feat (ushort gather).
// x8 edge unroll for MLP. EPI: 1 bias+relu, 2 bias+sigmoid.
// OB: 1 bf16 out (feeds next MFMA GEMM), 0 fp32 out (final).
template<int F, int EPI, int OB>
__global__ __launch_bounds__(256) void agg_kernel(const unsigned short* __restrict__ h,
                                                  const int* __restrict__ rowptr,
                                                  const int* __restrict__ col,
                                                  const float* __restrict__ val,
                                                  const float* __restrict__ bias,
                                                  void* __restrict__ outv, int n) {
    int wv = threadIdx.x >> 6;
    int lane = threadIdx.x & 63;
    int row = blockIdx.x * 4 + wv;
    if (row >= n) return;
    int e0 = rowptr[row], e1 = rowptr[row + 1];

    if (F == 128) {
        const unsigned short* hb = h + 2 * lane;
        float2 a0 = {0.f, 0.f}, a1 = {0.f, 0.f}, a2 = {0.f, 0.f}, a3 = {0.f, 0.f};
        float2 a4 = {0.f, 0.f}, a5 = {0.f, 0.f}, a6 = {0.f, 0.f}, a7 = {0.f, 0.f};
        int e = e0;
        for (; e + 8 <= e1; e += 8) {
            int s0 = col[e+0], s1 = col[e+1], s2 = col[e+2], s3 = col[e+3];
            int s4 = col[e+4], s5 = col[e+5], s6 = col[e+6], s7 = col[e+7];
            float v0 = val[e+0], v1 = val[e+1], v2 = val[e+2], v3 = val[e+3];
            float v4 = val[e+4], v5 = val[e+5], v6 = val[e+6], v7 = val[e+7];
            unsigned u0 = *(const unsigned*)&hb[(size_t)s0 * 128];
            unsigned u1 = *(const unsigned*)&hb[(size_t)s1 * 128];
            unsigned u2 = *(const unsigned*)&hb[(size_t)s2 * 128];
            unsigned u3 = *(const unsigned*)&hb[(size_t)s3 * 128];
            unsigned u4 = *(const unsigned*)&hb[(size_t)s4 * 128];
            unsigned u5 = *(const unsigned*)&hb[(size_t)s5 * 128];
            unsigned u6 = *(const unsigned*)&hb[(size_t)s6 * 128];
            unsigned u7 = *(const unsigned*)&hb[(size_t)s7 * 128];
            a0.x = fmaf(v0, bflo(u0), a0.x); a0.y = fmaf(v0, bfhi(u0), a0.y);
            a1.x = fmaf(v1, bflo(u1), a1.x); a1.y = fmaf(v1, bfhi(u1), a1.y);
            a2.x = fmaf(v2, bflo(u2), a2.x); a2.y = fmaf(v2, bfhi(u2), a2.y);
            a3.x = fmaf(v3, bflo(u3), a3.x); a3.y = fmaf(v3, bfhi(u3), a3.y);
            a4.x = fmaf(v4, bflo(u4), a4.x); a4.y = fmaf(v4, bfhi(u4), a4.y);
            a5.x = fmaf(v5, bflo(u5), a5.x); a5.y = fmaf(v5, bfhi(u5), a5.y);
            a6.x = fmaf(v6, bflo(u6), a6.x); a6.y = fmaf(v6, bfhi(u6), a6.y);
            a7.x = fmaf(v7, bflo(u7), a7.x); a7.y = fmaf(v7, bfhi(u7), a7.y);
        }
        if (e + 4 <= e1) {
            int s0 = col[e+0], s1 = col[e+1], s2 = col[e+2], s3 = col[e+3];
            float v0 = val[e+0], v1 = val[e+1], v2 = val[e+2], v3 = val[e+3];
            unsigned u0 = *(const unsigned*)&hb[(size_t)s0 * 128];
            unsigned u1 = *(const unsigned*)&hb[(size_t)s1 * 128];
            unsigned u2 = *(const unsigned*)&hb[(size_t)s2 * 128];
            unsigned u3 = *(const unsigned*)&hb[(size_t)s3 * 128];
            a0.x = fmaf(v0, bflo(u0), a0.x); a0.y = fmaf(v0, bfhi(u0), a0.y);
            a1.x = fmaf(v1, bflo(u1), a1.x); a1.y = fmaf(v1, bfhi(u1), a1.y);
            a2.x = fmaf(v2, bflo(u2), a2.x); a2.y = fmaf(v2, bfhi(u2), a2.y);
            a3.x = fmaf(v3, bflo(u3), a3.x); a3.y = fmaf(v3, bfhi(u3), a3.y);
            e += 4;
        }
        for (; e < e1; ++e) {
            float v = val[e];
            unsigned u = *(const unsigned*)&hb[(size_t)col[e] * 128];
            a0.x = fmaf(v, bflo(u), a0.x); a0.y = fmaf(v, bfhi(u), a0.y);
        }
        float2 r;
        r.x = ((a0.x + a1.x) + (a2.x + a3.x)) + ((a4.x + a5.x) + (a6.x + a7.x));
        r.y = ((a0.y + a1.y) + (a2.y + a3.y)) + ((a4.y + a5.y) + (a6.y + a7.y));
        if (EPI == 1) {
            r.x = fmaxf(r.x + bias[2 * lane + 0], 0.f);
            r.y = fmaxf(r.y + bias[2 * lane + 1], 0.f);
        }
        if (OB == 1) {
            unsigned pk = (unsigned)(unsigned short)f2bf(r.x)
                        | ((unsigned)(unsigned short)f2bf(r.y) << 16);
            ((unsigned*)outv)[(size_t)row * 64 + lane] = pk;
        } else {
            *(float2*)&((float*)outv)[(size_t)row * 128 + 2 * lane] = r;
        }
    } else {
        const unsigned short* hb = h + lane;
        float a0 = 0.f, a1 = 0.f, a2 = 0.f, a3 = 0.f;
        float a4 = 0.f, a5 = 0.f, a6 = 0.f, a7 = 0.f;
        int e = e0;
        for (; e + 8 <= e1; e += 8) {
            int s0 = col[e+0], s1 = col[e+1], s2 = col[e+2], s3 = col[e+3];
            int s4 = col[e+4], s5 = col[e+5], s6 = col[e+6], s7 = col[e+7];
            float v0 = val[e+0], v1 = val[e+1], v2 = val[e+2], v3 = val[e+3];
            float v4 = val[e+4], v5 = val[e+5], v6 = val[e+6], v7 = val[e+7];
            float g0 = bf1(hb[(size_t)s0 * 64]);
            float g1 = bf1(hb[(size_t)s1 * 64]);
            float g2 = bf1(hb[(size_t)s2 * 64]);
            float g3 = bf1(hb[(size_t)s3 * 64]);
            float g4 = bf1(hb[(size_t)s4 * 64]);
            float g5 = bf1(hb[(size_t)s5 * 64]);
            float g6 = bf1(hb[(size_t)s6 * 64]);
            float g7 = bf1(hb[(size_t)s7 * 64]);
            a0 = fmaf(v0, g0, a0); a1 = fmaf(v1, g1, a1);
            a2 = fmaf(v2, g2, a2); a3 = fmaf(v3, g3, a3);
            a4 = fmaf(v4, g4, a4); a5 = fmaf(v5, g5, a5);
            a6 = fmaf(v6, g6, a6); a7 = fmaf(v7, g7, a7);
        }
        if (e + 4 <= e1) {
            int s0 = col[e+0], s1 = col[e+1], s2 = col[e+2], s3 = col[e+3];
            float v0 = val[e+0], v1 = val[e+1], v2 = val[e+2], v3 = val[e+3];
            a0 = fmaf(v0, bf1(hb[(size_t)s0 * 64]), a0);
            a1 = fmaf(v1, bf1(hb[(size_t)s1 * 64]), a1);
            a2 = fmaf(v2, bf1(hb[(size_t)s2 * 64]), a2);
            a3 = fmaf(v3, bf1(hb[(size_t)s3 * 64]), a3);
            e += 4;
        }
        for (; e < e1; ++e) a0 = fmaf(val[e], bf1(hb[(size_t)col[e] * 64]), a0);
        float acc = ((a0 + a1) + (a2 + a3)) + ((a4 + a5) + (a6 + a7));
        if (EPI == 2) {
            acc += bias[lane];
            acc = 1.0f / (1.0f + __expf(-acc));
        }
        ((float*)outv)[(size_t)row * 64 + lane] = acc;
    }
}

// ---------------- launch ----------------

extern "C" void kernel_launch(void* const* d_in, const int* in_sizes, int n_in,
                              void* d_out, int out_size, void* d_ws, size_t ws_size,
                              hipStream_t stream) {
    const float* x  = (const float*)d_in[0];
    const int*   ei = (const int*)d_in[1];
    const float* ew = (const float*)d_in[2];
    const float* W1 = (const float*)d_in[3];
    const float* b1 = (const float*)d_in[4];
    const float* W2 = (const float*)d_in[5];
    const float* b2 = (const float*)d_in[6];
    const float* W3 = (const float*)d_in[7];
    const float* b3 = (const float*)d_in[8];
    const float* W4 = (const float*)d_in[9];
    const float* b4 = (const float*)d_in[10];

    const int N = in_sizes[0] / FIN;        // 50000
    const int E = in_sizes[1] / 2;          // 800000
    const int M = N + E;                    // CSR entries incl self-loops
    const int* srcI = ei;                   // edge_index[0]
    const int* dstI = ei + E;               // edge_index[1]

    // carve workspace (256B aligned)
    char* p = (char*)d_ws;
    auto alloc = [&](size_t bytes) -> void* {
        void* r = (void*)p;
        p += (bytes + 255) & ~(size_t)255;
        return r;
    };
    float* dinv   = (float*)alloc((size_t)N * 4);
    int*   cnt    = (int*)  alloc((size_t)N * 4);
    int*   rowptr = (int*)  alloc((size_t)(N + 1) * 4);
    unsigned short* posr = (unsigned short*)alloc((size_t)E * 2);
    int*   col    = (int*)  alloc((size_t)M * 4);
    float* val    = (float*)alloc((size_t)M * 4);
    int*   bsums  = (int*)  alloc(256 * 4);
    short* B      = (short*)alloc((size_t)N * 128 * 2);   // GEMM outputs (bf16)
    short* G      = (short*)alloc((size_t)N * 128 * 2);   // agg outputs (bf16)
    short* Wt1    = (short*)alloc(16384 * 2);
    short* Wt2    = (short*)alloc(16384 * 2);
    short* Wt3    = (short*)alloc(16384 * 2);
    short* Wt4    = (short*)alloc(8192 * 2);

    int gN = (N + 255) / 256;
    int gG = (N + 63) / 64;
    int gA = (N + 3) / 4;
    int gM = (N + E + 255) / 256;
    int nchunks = (N + 1023) / 1024;

    init_cnt<<<gN, 256, 0, stream>>>(cnt, N);
    prep_wt<<<224, 256, 0, stream>>>(W1, W2, W3, W4, Wt1, Wt2, Wt3, Wt4);
    // one atomic pass (hist) fused with layer-1 MFMA GEMM B = x@W1 (bf16 out)
    fused_hist_gemm1<<<HIST_BLOCKS + gG, 256, 0, stream>>>(dstI, cnt, posr, E,
                                                           x, Wt1, B, N);
    scan_chunk<<<nchunks, 256, 0, stream>>>(cnt, rowptr, bsums, N);
    scan_tops<<<1, 1, 0, stream>>>(bsums, nchunks, rowptr);
    scan_add<<<gN, 256, 0, stream>>>(rowptr, bsums, N);
    scatter_csr<<<gM, 256, 0, stream>>>(srcI, dstI, ew, posr, rowptr, col, val, N, E);
    row_dinv<<<gN, 256, 0, stream>>>(rowptr, val, dinv, N);
    scale_val<<<gM, 256, 0, stream>>>(srcI, dstI, posr, rowptr, dinv, val, N, E);

    // L1: B = x@W1 (done); A1 = relu(agg(B)+b1) -> G (bf16)
    agg_kernel<128, 1, 1><<<gA, 256, 0, stream>>>((const unsigned short*)B, rowptr, col, val, b1, G, N);
    // L2: B = G@W2 ; A2 = relu(agg(B)+b2) -> G
    mgemm_kernel<128, false><<<gG, 256, 0, stream>>>(G, Wt2, B, N);
    agg_kernel<128, 1, 1><<<gA, 256, 0, stream>>>((const unsigned short*)B, rowptr, col, val, b2, G, N);
    // L3
    mgemm_kernel<128, false><<<gG, 256, 0, stream>>>(G, Wt3, B, N);
    agg_kernel<128, 1, 1><<<gA, 256, 0, stream>>>((const unsigned short*)B, rowptr, col, val, b3, G, N);
    // L4: B = G@W4 (64 cols, bf16); out = sigmoid(agg(B)+b4) (fp32)
    mgemm_kernel<64, false><<<gG, 256, 0, stream>>>(G, Wt4, B, N);
    agg_kernel<64, 2, 0><<<gA, 256, 0, stream>>>((const unsigned short*)B, rowptr, col, val, b4, d_out, N);
}

// Round 12
// 407.992 us; speedup vs baseline: 1.6087x; 1.0258x over previous
//
#include <hip/hip_runtime.h>
#include <hip/hip_bf16.h>
#include <math.h>

// GCN 4-layer forward on MI355X.
// N=50000 nodes, E=800000 edges, IN=H=128, OUT=64.
// R9 counters: fused_hist_gemm1 54us is top (MfmaUtil 1%, VALU 3%, Occ 33%)
//   -> 800K returning atomics on 256 hist blocks dominate; GEMM half ~10us
//   finishes early; machine idles. Device atomic throughput ~20/ns (R4 x-check)
//   -> floor ~38-40us for 800K.
// R10 changes:
//   (a) histogram distributed across ALL fused-kernel blocks (grid-stride,
//       4-deep atomic batches issued before the GEMM body) -> full issue rate,
//       GEMM work hides atomic latency.
//   (b) scan_tops: serial 1-thread loop (49 dependent round-trips) -> 64-lane
//       shfl_up scan.
//   (c) init_cnt merged into prep_wt (one fewer launch).
// Pipeline: one atomic pass (hist fused w/ gemm1) -> atomic-free CSR ->
//   per layer: MFMA GEMM (bf16 in/out, no LDS) -> agg(+bias+act, bf16 gathers).

#define FIN 128

typedef __attribute__((ext_vector_type(8))) short bfrag;   // 8 bf16 = 4 VGPR
typedef __attribute__((ext_vector_type(4))) float f32x4;   // MFMA acc

__device__ __forceinline__ short f2bf(float f) {           // RNE float->bf16
    union { float f; unsigned u; } v; v.f = f;
    unsigned r = v.u + 0x7fff + ((v.u >> 16) & 1);
    return (short)(r >> 16);
}
__device__ __forceinline__ float bflo(unsigned u) {        // low bf16 -> f32
    union { unsigned x; float f; } c; c.x = u << 16; return c.f;
}
__device__ __forceinline__ float bfhi(unsigned u) {        // high bf16 -> f32
    union { unsigned x; float f; } c; c.x = u & 0xffff0000u; return c.f;
}
__device__ __forceinline__ float bf1(unsigned short u) {
    union { unsigned x; float f; } c; c.x = (unsigned)u << 16; return c.f;
}

// ---------------- precompute kernels ----------------

// transpose+cast W1..W4 (fp32 [k][n]) -> Wt (bf16 [n][k]); also init cnt=1.
// grid 224*256 = 57344 threads = exactly 3*16384 + 8192 Wt elems; covers N.
__global__ void prep_wt(const float* __restrict__ W1, const float* __restrict__ W2,
                        const float* __restrict__ W3, const float* __restrict__ W4,
                        short* __restrict__ Wt1, short* __restrict__ Wt2,
                        short* __restrict__ Wt3, short* __restrict__ Wt4,
                        int* __restrict__ cnt, int n) {
    int i = blockIdx.x * 256 + threadIdx.x;
    if (i < n) cnt[i] = 1;               // slot 0 reserved for self-loop
    if (i < 3 * 16384) {
        int m = i >> 14, r = i & 16383;
        const float* W = (m == 0) ? W1 : (m == 1) ? W2 : W3;
        short* Wt = (m == 0) ? Wt1 : (m == 1) ? Wt2 : Wt3;
        int nn = r >> 7, k = r & 127;
        Wt[r] = f2bf(W[k * 128 + nn]);
    } else {
        int r = i - 3 * 16384;                        // W4: [128][64] -> Wt4 [64][128]
        if (r < 8192) {
            int nn = r >> 7, k = r & 127;
            Wt4[nn * 128 + k] = f2bf(W4[k * 64 + nn]);
        }
    }
}

// 3-pass exclusive scan of cnt[] into rowptr[]
__global__ void scan_chunk(const int* __restrict__ cnt, int* __restrict__ rowptr,
                           int* __restrict__ bsums, int n) {
    __shared__ int sd[256];
    int t = threadIdx.x;
    int base = blockIdx.x * 1024;
    int v[4]; int local = 0;
#pragma unroll
    for (int j = 0; j < 4; j++) {
        int idx = base + t * 4 + j;
        v[j] = (idx < n) ? cnt[idx] : 0;
        local += v[j];
    }
    sd[t] = local;
    __syncthreads();
    for (int off = 1; off < 256; off <<= 1) {
        int x = (t >= off) ? sd[t - off] : 0;
        __syncthreads();
        sd[t] += x;
        __syncthreads();
    }
    int run = sd[t] - local;
#pragma unroll
    for (int j = 0; j < 4; j++) {
        int idx = base + t * 4 + j;
        run += v[j];
        if (idx < n) rowptr[idx + 1] = run;
    }
    if (t == 255) bsums[blockIdx.x] = sd[255];
}

// parallel wave scan of chunk sums (nchunks <= 64)
__global__ void scan_tops(int* bsums, int nchunks, int* rowptr) {
    int l = threadIdx.x;                     // 64 threads
    if (l == 0) rowptr[0] = 0;
    int v = (l < nchunks) ? bsums[l] : 0;
#pragma unroll
    for (int off = 1; off < 64; off <<= 1) {
        int u = __shfl_up(v, off);
        if (l >= off) v += u;
    }
    if (l < nchunks) bsums[l] = v;
}

__global__ void scan_add(int* rowptr, const int* __restrict__ bsums, int n) {
    int i = blockIdx.x * 256 + threadIdx.x;
    if (i < n) {
        int c = i >> 10;
        if (c > 0) rowptr[i + 1] += bsums[c - 1];
    }
}

// atomic-free CSR fill using saved per-edge slots
__global__ void scatter_csr(const int* __restrict__ src, const int* __restrict__ dst,
                            const float* __restrict__ ew, const unsigned short* __restrict__ posr,
                            const int* __restrict__ rowptr,
                            int* __restrict__ col, float* __restrict__ val, int n, int e) {
    int i = blockIdx.x * 256 + threadIdx.x;
    if (i < n) {
        int p = rowptr[i];
        col[p] = i;
        val[p] = 1.0f;                   // raw self-loop weight
    } else if (i < n + e) {
        int k = i - n;
        int d = dst[k];
        int p = rowptr[d] + (int)posr[k];
        col[p] = src[k];
        val[p] = ew[k];                  // raw weight; scaled later
    }
}

__global__ void row_dinv(const int* __restrict__ rowptr, const float* __restrict__ val,
                         float* __restrict__ dinv, int n) {
    int i = blockIdx.x * 256 + threadIdx.x;
    if (i < n) {
        int a = rowptr[i], b = rowptr[i + 1];
        float s = 0.f;
        for (int k = a; k < b; k++) s += val[k];
        dinv[i] = rsqrtf(s);             // s >= 1 (self-loop)
    }
}

__global__ void scale_val(const int* __restrict__ src, const int* __restrict__ dst,
                          const unsigned short* __restrict__ posr, const int* __restrict__ rowptr,
                          const float* __restrict__ dinv, float* __restrict__ val, int n, int e) {
    int i = blockIdx.x * 256 + threadIdx.x;
    if (i < n) {
        val[rowptr[i]] = dinv[i] * dinv[i];
    } else if (i < n + e) {
        int k = i - n;
        int s = src[k], d = dst[k];
        val[rowptr[d] + (int)posr[k]] *= dinv[s] * dinv[d];
    }
}

// ---------------- MFMA GEMM (bf16 in, bf16 out), no LDS ----------------
// Block = 256 thr = 4 waves; wave owns 16 rows x NOUT cols. K = 128 fixed.
// A: row = lane&15, k = (lane>>4)*8 + j. B from Wt[n][k] bf16.
// D: col = lane&15, row = (lane>>4)*4 + reg.
// AFP32: load A as fp32 and cvt (layer-1 reads x).
template<int NOUT, bool AFP32>
__device__ __forceinline__ void mgemm_body(int mblk, const void* Ain,
                                           const short* __restrict__ Wt,
                                           short* __restrict__ out, int nrows) {
    constexpr int NT = NOUT / 16;
    int l = threadIdx.x & 63;
    int lr = l & 15;
    int kg = l >> 4;
    int m0 = mblk * 64 + (threadIdx.x >> 6) * 16;
    int arow = m0 + lr;
    bool rowok = arow < nrows;

    bfrag a[4];
    if (AFP32) {
        const float* A = (const float*)Ain + (size_t)arow * 128 + kg * 8;
#pragma unroll
        for (int kc = 0; kc < 4; kc++) {
            bfrag t;
            if (rowok) {
                float4 u0 = *(const float4*)(A + kc * 32);
                float4 u1 = *(const float4*)(A + kc * 32 + 4);
                t[0] = f2bf(u0.x); t[1] = f2bf(u0.y); t[2] = f2bf(u0.z); t[3] = f2bf(u0.w);
                t[4] = f2bf(u1.x); t[5] = f2bf(u1.y); t[6] = f2bf(u1.z); t[7] = f2bf(u1.w);
            } else {
#pragma unroll
                for (int j = 0; j < 8; j++) t[j] = 0;
            }
            a[kc] = t;
        }
    } else {
        const short* A = (const short*)Ain + (size_t)arow * 128 + kg * 8;
#pragma unroll
        for (int kc = 0; kc < 4; kc++) {
            if (rowok) {
                a[kc] = *(const bfrag*)(A + kc * 32);
            } else {
#pragma unroll
                for (int j = 0; j < 8; j++) a[kc][j] = 0;
            }
        }
    }

    f32x4 acc[NT];
#pragma unroll
    for (int t = 0; t < NT; t++)
#pragma unroll
        for (int j = 0; j < 4; j++) acc[t][j] = 0.f;

#pragma unroll
    for (int nt = 0; nt < NT; nt++) {
        const short* Wc = Wt + (size_t)(nt * 16 + lr) * 128 + kg * 8;
#pragma unroll
        for (int kc = 0; kc < 4; kc++) {
            bfrag b = *(const bfrag*)(Wc + kc * 32);
            acc[nt] = __builtin_amdgcn_mfma_f32_16x16x32_bf16(a[kc], b, acc[nt], 0, 0, 0);
        }
    }

#pragma unroll
    for (int nt = 0; nt < NT; nt++) {
#pragma unroll
        for (int r = 0; r < 4; r++) {
            int orow = m0 + kg * 4 + r;
            if (orow >= nrows) continue;
            int ocol = nt * 16 + lr;
            out[(size_t)orow * NOUT + ocol] = f2bf(acc[nt][r]);
        }
    }
}

template<int NOUT, bool AFP32>
__global__ __launch_bounds__(256) void mgemm_kernel(const void* __restrict__ Ain,
                                                    const short* __restrict__ Wt,
                                                    short* __restrict__ out, int nrows) {
    mgemm_body<NOUT, AFP32>(blockIdx.x, Ain, Wt, out, nrows);
}

// ---------------- fused: dst-histogram (all blocks) + layer-1 MFMA GEMM ----------------
// Every block: grid-stride slice of edges (4-deep atomic batches issued first,
// latency drains under the GEMM), then its GEMM tile.
__global__ __launch_bounds__(256) void fused_hist_gemm1(const int* __restrict__ dst,
                                                        int* __restrict__ cnt,
                                                        unsigned short* __restrict__ posr, int e,
                                                        const float* __restrict__ x,
                                                        const short* __restrict__ Wt1,
                                                        short* __restrict__ B, int nrows) {
    const int stride = gridDim.x * 256;
    int i = blockIdx.x * 256 + threadIdx.x;
    for (; i + 3 * stride < e; i += 4 * stride) {
        int d0 = dst[i];
        int d1 = dst[i + stride];
        int d2 = dst[i + 2 * stride];
        int d3 = dst[i + 3 * stride];
        int p0 = atomicAdd(&cnt[d0], 1);
        int p1 = atomicAdd(&cnt[d1], 1);
        int p2 = atomicAdd(&cnt[d2], 1);
        int p3 = atomicAdd(&cnt[d3], 1);
        posr[i]              = (unsigned short)p0;
        posr[i + stride]     = (unsigned short)p1;
        posr[i + 2 * stride] = (unsigned short)p2;
        posr[i + 3 * stride] = (unsigned short)p3;
    }
    for (; i < e; i += stride) posr[i] = (unsigned short)atomicAdd(&cnt[dst[i]], 1);

    mgemm_body<128, true>(blockIdx.x, x, Wt1, B, nrows);
}

// ---------------- aggregation (bf16 gathers) ----------------
// 256-thread block = 4 waves; wave handles one row. F=128: lane owns 2 feats
// (one dword = 2 bf16 per gather); F=64: lane owns 1 feat (ushort gather).
// x8 edge unroll for MLP. EPI: 1 bias+relu, 2 bias+sigmoid.
// OB: 1 bf16 out (feeds next MFMA GEMM), 0 fp32 out (final).
template<int F, int EPI, int OB>
__global__ __launch_bounds__(256) void agg_kernel(const unsigned short* __restrict__ h,
                                                  const int* __restrict__ rowptr,
                                                  const int* __restrict__ col,
                                                  const float* __restrict__ val,
                                                  const float* __restrict__ bias,
                                                  void* __restrict__ outv, int n) {
    int wv = threadIdx.x >> 6;
    int lane = threadIdx.x & 63;
    int row = blockIdx.x * 4 + wv;
    if (row >= n) return;
    int e0 = rowptr[row], e1 = rowptr[row + 1];

    if (F == 128) {
        const unsigned short* hb = h + 2 * lane;
        float2 a0 = {0.f, 0.f}, a1 = {0.f, 0.f}, a2 = {0.f, 0.f}, a3 = {0.f, 0.f};
        float2 a4 = {0.f, 0.f}, a5 = {0.f, 0.f}, a6 = {0.f, 0.f}, a7 = {0.f, 0.f};
        int e = e0;
        for (; e + 8 <= e1; e += 8) {
            int s0 = col[e+0], s1 = col[e+1], s2 = col[e+2], s3 = col[e+3];
            int s4 = col[e+4], s5 = col[e+5], s6 = col[e+6], s7 = col[e+7];
            float v0 = val[e+0], v1 = val[e+1], v2 = val[e+2], v3 = val[e+3];
            float v4 = val[e+4], v5 = val[e+5], v6 = val[e+6], v7 = val[e+7];
            unsigned u0 = *(const unsigned*)&hb[(size_t)s0 * 128];
            unsigned u1 = *(const unsigned*)&hb[(size_t)s1 * 128];
            unsigned u2 = *(const unsigned*)&hb[(size_t)s2 * 128];
            unsigned u3 = *(const unsigned*)&hb[(size_t)s3 * 128];
            unsigned u4 = *(const unsigned*)&hb[(size_t)s4 * 128];
            unsigned u5 = *(const unsigned*)&hb[(size_t)s5 * 128];
            unsigned u6 = *(const unsigned*)&hb[(size_t)s6 * 128];
            unsigned u7 = *(const unsigned*)&hb[(size_t)s7 * 128];
            a0.x = fmaf(v0, bflo(u0), a0.x); a0.y = fmaf(v0, bfhi(u0), a0.y);
            a1.x = fmaf(v1, bflo(u1), a1.x); a1.y = fmaf(v1, bfhi(u1), a1.y);
            a2.x = fmaf(v2, bflo(u2), a2.x); a2.y = fmaf(v2, bfhi(u2), a2.y);
            a3.x = fmaf(v3, bflo(u3), a3.x); a3.y = fmaf(v3, bfhi(u3), a3.y);
            a4.x = fmaf(v4, bflo(u4), a4.x); a4.y = fmaf(v4, bfhi(u4), a4.y);
            a5.x = fmaf(v5, bflo(u5), a5.x); a5.y = fmaf(v5, bfhi(u5), a5.y);
            a6.x = fmaf(v6, bflo(u6), a6.x); a6.y = fmaf(v6, bfhi(u6), a6.y);
            a7.x = fmaf(v7, bflo(u7), a7.x); a7.y = fmaf(v7, bfhi(u7), a7.y);
        }
        if (e + 4 <= e1) {
            int s0 = col[e+0], s1 = col[e+1], s2 = col[e+2], s3 = col[e+3];
            float v0 = val[e+0], v1 = val[e+1], v2 = val[e+2], v3 = val[e+3];
            unsigned u0 = *(const unsigned*)&hb[(size_t)s0 * 128];
            unsigned u1 = *(const unsigned*)&hb[(size_t)s1 * 128];
            unsigned u2 = *(const unsigned*)&hb[(size_t)s2 * 128];
            unsigned u3 = *(const unsigned*)&hb[(size_t)s3 * 128];
            a0.x = fmaf(v0, bflo(u0), a0.x); a0.y = fmaf(v0, bfhi(u0), a0.y);
            a1.x = fmaf(v1, bflo(u1), a1.x); a1.y = fmaf(v1, bfhi(u1), a1.y);
            a2.x = fmaf(v2, bflo(u2), a2.x); a2.y = fmaf(v2, bfhi(u2), a2.y);
            a3.x = fmaf(v3, bflo(u3), a3.x); a3.y = fmaf(v3, bfhi(u3), a3.y);
            e += 4;
        }
        for (; e < e1; ++e) {
            float v = val[e];
            unsigned u = *(const unsigned*)&hb[(size_t)col[e] * 128];
            a0.x = fmaf(v, bflo(u), a0.x); a0.y = fmaf(v, bfhi(u), a0.y);
        }
        float2 r;
        r.x = ((a0.x + a1.x) + (a2.x + a3.x)) + ((a4.x + a5.x) + (a6.x + a7.x));
        r.y = ((a0.y + a1.y) + (a2.y + a3.y)) + ((a4.y + a5.y) + (a6.y + a7.y));
        if (EPI == 1) {
            r.x = fmaxf(r.x + bias[2 * lane + 0], 0.f);
            r.y = fmaxf(r.y + bias[2 * lane + 1], 0.f);
        }
        if (OB == 1) {
            unsigned pk = (unsigned)(unsigned short)f2bf(r.x)
                        | ((unsigned)(unsigned short)f2bf(r.y) << 16);
            ((unsigned*)outv)[(size_t)row * 64 + lane] = pk;
        } else {
            *(float2*)&((float*)outv)[(size_t)row * 128 + 2 * lane] = r;
        }
    } else {
        const unsigned short* hb = h + lane;
        float a0 = 0.f, a1 = 0.f, a2 = 0.f, a3 = 0.f;
        float a4 = 0.f, a5 = 0.f, a6 = 0.f, a7 = 0.f;
        int e = e0;
        for (; e + 8 <= e1; e += 8) {
            int s0 = col[e+0], s1 = col[e+1], s2 = col[e+2], s3 = col[e+3];
            int s4 = col[e+4], s5 = col[e+5], s6 = col[e+6], s7 = col[e+7];
            float v0 = val[e+0], v1 = val[e+1], v2 = val[e+2], v3 = val[e+3];
            float v4 = val[e+4], v5 = val[e+5], v6 = val[e+6], v7 = val[e+7];
            float g0 = bf1(hb[(size_t)s0 * 64]);
            float g1 = bf1(hb[(size_t)s1 * 64]);
            float g2 = bf1(hb[(size_t)s2 * 64]);
            float g3 = bf1(hb[(size_t)s3 * 64]);
            float g4 = bf1(hb[(size_t)s4 * 64]);
            float g5 = bf1(hb[(size_t)s5 * 64]);
            float g6 = bf1(hb[(size_t)s6 * 64]);
            float g7 = bf1(hb[(size_t)s7 * 64]);
            a0 = fmaf(v0, g0, a0); a1 = fmaf(v1, g1, a1);
            a2 = fmaf(v2, g2, a2); a3 = fmaf(v3, g3, a3);
            a4 = fmaf(v4, g4, a4); a5 = fmaf(v5, g5, a5);
            a6 = fmaf(v6, g6, a6); a7 = fmaf(v7, g7, a7);
        }
        if (e + 4 <= e1) {
            int s0 = col[e+0], s1 = col[e+1], s2 = col[e+2], s3 = col[e+3];
            float v0 = val[e+0], v1 = val[e+1], v2 = val[e+2], v3 = val[e+3];
            a0 = fmaf(v0, bf1(hb[(size_t)s0 * 64]), a0);
            a1 = fmaf(v1, bf1(hb[(size_t)s1 * 64]), a1);
            a2 = fmaf(v2, bf1(hb[(size_t)s2 * 64]), a2);
            a3 = fmaf(v3, bf1(hb[(size_t)s3 * 64]), a3);
            e += 4;
        }
        for (; e < e1; ++e) a0 = fmaf(val[e], bf1(hb[(size_t)col[e] * 64]), a0);
        float acc = ((a0 + a1) + (a2 + a3)) + ((a4 + a5) + (a6 + a7));
        if (EPI == 2) {
            acc += bias[lane];
            acc = 1.0f / (1.0f + __expf(-acc));
        }
        ((float*)outv)[(size_t)row * 64 + lane] = acc;
    }
}

// ---------------- launch ----------------

extern "C" void kernel_launch(void* const* d_in, const int* in_sizes, int n_in,
                              void* d_out, int out_size, void* d_ws, size_t ws_size,
                              hipStream_t stream) {
    const float* x  = (const float*)d_in[0];
    const int*   ei = (const int*)d_in[1];
    const float* ew = (const float*)d_in[2];
    const float* W1 = (const float*)d_in[3];
    const float* b1 = (const float*)d_in[4];
    const float* W2 = (const float*)d_in[5];
    const float* b2 = (const float*)d_in[6];
    const float* W3 = (const float*)d_in[7];
    const float* b3 = (const float*)d_in[8];
    const float* W4 = (const float*)d_in[9];
    const float* b4 = (const float*)d_in[10];

    const int N = in_sizes[0] / FIN;        // 50000
    const int E = in_sizes[1] / 2;          // 800000
    const int M = N + E;                    // CSR entries incl self-loops
    const int* srcI = ei;                   // edge_index[0]
    const int* dstI = ei + E;               // edge_index[1]

    // carve workspace (256B aligned)
    char* p = (char*)d_ws;
    auto alloc = [&](size_t bytes) -> void* {
        void* r = (void*)p;
        p += (bytes + 255) & ~(size_t)255;
        return r;
    };
    float* dinv   = (float*)alloc((size_t)N * 4);
    int*   cnt    = (int*)  alloc((size_t)N * 4);
    int*   rowptr = (int*)  alloc((size_t)(N + 1) * 4);
    unsigned short* posr = (unsigned short*)alloc((size_t)E * 2);
    int*   col    = (int*)  alloc((size_t)M * 4);
    float* val    = (float*)alloc((size_t)M * 4);
    int*   bsums  = (int*)  alloc(256 * 4);
    short* B      = (short*)alloc((size_t)N * 128 * 2);   // GEMM outputs (bf16)
    short* G      = (short*)alloc((size_t)N * 128 * 2);   // agg outputs (bf16)
    short* Wt1    = (short*)alloc(16384 * 2);
    short* Wt2    = (short*)alloc(16384 * 2);
    short* Wt3    = (short*)alloc(16384 * 2);
    short* Wt4    = (short*)alloc(8192 * 2);

    int gN = (N + 255) / 256;
    int gG = (N + 63) / 64;
    int gA = (N + 3) / 4;
    int gM = (N + E + 255) / 256;
    int nchunks = (N + 1023) / 1024;

    // prep weights + init cnt (one kernel)
    prep_wt<<<224, 256, 0, stream>>>(W1, W2, W3, W4, Wt1, Wt2, Wt3, Wt4, cnt, N);
    // one atomic pass (hist, all blocks) fused with layer-1 MFMA GEMM B = x@W1
    fused_hist_gemm1<<<gG, 256, 0, stream>>>(dstI, cnt, posr, E, x, Wt1, B, N);
    scan_chunk<<<nchunks, 256, 0, stream>>>(cnt, rowptr, bsums, N);
    scan_tops<<<1, 64, 0, stream>>>(bsums, nchunks, rowptr);
    scan_add<<<gN, 256, 0, stream>>>(rowptr, bsums, N);
    scatter_csr<<<gM, 256, 0, stream>>>(srcI, dstI, ew, posr, rowptr, col, val, N, E);
    row_dinv<<<gN, 256, 0, stream>>>(rowptr, val, dinv, N);
    scale_val<<<gM, 256, 0, stream>>>(srcI, dstI, posr, rowptr, dinv, val, N, E);

    // L1: B = x@W1 (done); A1 = relu(agg(B)+b1) -> G (bf16)
    agg_kernel<128, 1, 1><<<gA, 256, 0, stream>>>((const unsigned short*)B, rowptr, col, val, b1, G, N);
    // L2: B = G@W2 ; A2 = relu(agg(B)+b2) -> G
    mgemm_kernel<128, false><<<gG, 256, 0, stream>>>(G, Wt2, B, N);
    agg_kernel<128, 1, 1><<<gA, 256, 0, stream>>>((const unsigned short*)B, rowptr, col, val, b2, G, N);
    // L3
    mgemm_kernel<128, false><<<gG, 256, 0, stream>>>(G, Wt3, B, N);
    agg_kernel<128, 1, 1><<<gA, 256, 0, stream>>>((const unsigned short*)B, rowptr, col, val, b3, G, N);
    // L4: B = G@W4 (64 cols, bf16); out = sigmoid(agg(B)+b4) (fp32)
    mgemm_kernel<64, false><<<gG, 256, 0, stream>>>(G, Wt4, B, N);
    agg_kernel<64, 2, 0><<<gA, 256, 0, stream>>>((const unsigned short*)B, rowptr, col, val, b4, d_out, N);
}

// Round 13
// 365.459 us; speedup vs baseline: 1.7959x; 1.1164x over previous
//
#include <hip/hip_runtime.h>
#include <hip/hip_bf16.h>
#include <math.h>

// GCN 4-layer forward on MI355X.
// N=50000 nodes, E=800000 edges, IN=H=128, OUT=64.
// R12 post-mortem: grid-wide hist did NOT speed atomics (54->59us; rate
//   ~16-18 atomics/ns is parallelism-independent -> device floor). Total
//   gain came from scan_tops fix + merged init.
// R13 changes:
//   (a) hist reverted to R9's measured-best 256-dedicated-block form (54us).
//   (b) agg fused with NEXT layer's GEMM: 16 rows/block staged in padded LDS
//       [16][136] bf16, then 4 waves MFMA 16xNOUT/4 slices. Deletes 3 mgemm
//       dispatches + the G buffer (Ba/Bb ping-pong).
//   (c) scan_tops absorbed into scan_add (per-block wave scan); scale_val ->
//       row-order scale_row (sequential val, L2-resident dinv gathers).
// Pipeline: prep_wt -> fused(hist+gemm1) -> scan -> scatter -> dinv -> scale
//   -> 3x agg_gemm -> agg64(sigmoid).

#define FIN 128
#define HIST_BLOCKS 256

typedef __attribute__((ext_vector_type(8))) short bfrag;   // 8 bf16 = 4 VGPR
typedef __attribute__((ext_vector_type(4))) float f32x4;   // MFMA acc

__device__ __forceinline__ short f2bf(float f) {           // RNE float->bf16
    union { float f; unsigned u; } v; v.f = f;
    unsigned r = v.u + 0x7fff + ((v.u >> 16) & 1);
    return (short)(r >> 16);
}
__device__ __forceinline__ float bflo(unsigned u) {
    union { unsigned x; float f; } c; c.x = u << 16; return c.f;
}
__device__ __forceinline__ float bfhi(unsigned u) {
    union { unsigned x; float f; } c; c.x = u & 0xffff0000u; return c.f;
}
__device__ __forceinline__ float bf1(unsigned short u) {
    union { unsigned x; float f; } c; c.x = (unsigned)u << 16; return c.f;
}

// ---------------- precompute kernels ----------------

// transpose+cast W1..W4 (fp32 [k][n]) -> Wt (bf16 [n][k]); also init cnt=1.
__global__ void prep_wt(const float* __restrict__ W1, const float* __restrict__ W2,
                        const float* __restrict__ W3, const float* __restrict__ W4,
                        short* __restrict__ Wt1, short* __restrict__ Wt2,
                        short* __restrict__ Wt3, short* __restrict__ Wt4,
                        int* __restrict__ cnt, int n) {
    int i = blockIdx.x * 256 + threadIdx.x;
    if (i < n) cnt[i] = 1;               // slot 0 reserved for self-loop
    if (i < 3 * 16384) {
        int m = i >> 14, r = i & 16383;
        const float* W = (m == 0) ? W1 : (m == 1) ? W2 : W3;
        short* Wt = (m == 0) ? Wt1 : (m == 1) ? Wt2 : Wt3;
        int nn = r >> 7, k = r & 127;
        Wt[r] = f2bf(W[k * 128 + nn]);
    } else {
        int r = i - 3 * 16384;           // W4: [128][64] -> Wt4 [64][128]
        if (r < 8192) {
            int nn = r >> 7, k = r & 127;
            Wt4[nn * 128 + k] = f2bf(W4[k * 64 + nn]);
        }
    }
}

// pass 1: per-1024-chunk inclusive scan into rowptr[i+1], chunk sums to bsums
__global__ void scan_chunk(const int* __restrict__ cnt, int* __restrict__ rowptr,
                           int* __restrict__ bsums, int n) {
    __shared__ int sd[256];
    int t = threadIdx.x;
    int base = blockIdx.x * 1024;
    int v[4]; int local = 0;
#pragma unroll
    for (int j = 0; j < 4; j++) {
        int idx = base + t * 4 + j;
        v[j] = (idx < n) ? cnt[idx] : 0;
        local += v[j];
    }
    sd[t] = local;
    __syncthreads();
    for (int off = 1; off < 256; off <<= 1) {
        int x = (t >= off) ? sd[t - off] : 0;
        __syncthreads();
        sd[t] += x;
        __syncthreads();
    }
    int run = sd[t] - local;
#pragma unroll
    for (int j = 0; j < 4; j++) {
        int idx = base + t * 4 + j;
        run += v[j];
        if (idx < n) rowptr[idx + 1] = run;
    }
    if (t == 255) bsums[blockIdx.x] = sd[255];
}

// pass 2: each block wave-scans bsums in LDS, then adds chunk prefix.
__global__ void scan_add(int* rowptr, const int* __restrict__ bsums, int n, int nchunks) {
    __shared__ int pref[64];
    if (threadIdx.x < 64) {
        int l = threadIdx.x;
        int v = (l < nchunks) ? bsums[l] : 0;
#pragma unroll
        for (int off = 1; off < 64; off <<= 1) {
            int u = __shfl_up(v, off);
            if (l >= off) v += u;
        }
        pref[l] = v;
    }
    __syncthreads();
    int i = blockIdx.x * 256 + threadIdx.x;
    if (i == 0) rowptr[0] = 0;
    if (i < n) {
        int c = i >> 10;
        if (c > 0) rowptr[i + 1] += pref[c - 1];
    }
}

// atomic-free CSR fill using saved per-edge slots
__global__ void scatter_csr(const int* __restrict__ src, const int* __restrict__ dst,
                            const float* __restrict__ ew, const unsigned short* __restrict__ posr,
                            const int* __restrict__ rowptr,
                            int* __restrict__ col, float* __restrict__ val, int n, int e) {
    int i = blockIdx.x * 256 + threadIdx.x;
    if (i < n) {
        int p = rowptr[i];
        col[p] = i;
        val[p] = 1.0f;                   // raw self-loop weight
    } else if (i < n + e) {
        int k = i - n;
        int d = dst[k];
        int p = rowptr[d] + (int)posr[k];
        col[p] = src[k];
        val[p] = ew[k];                  // raw weight; scaled by scale_row
    }
}

__global__ void row_dinv(const int* __restrict__ rowptr, const float* __restrict__ val,
                         float* __restrict__ dinv, int n) {
    int i = blockIdx.x * 256 + threadIdx.x;
    if (i < n) {
        int a = rowptr[i], b = rowptr[i + 1];
        float s = 0.f;
        for (int k = a; k < b; k++) s += val[k];
        dinv[i] = rsqrtf(s);             // s >= 1 (self-loop)
    }
}

// row-order scaling: sequential val/col, dinv gathers L2-resident (200KB).
// self-loop entry (raw 1.0, col=i) becomes dinv_i^2 automatically.
__global__ void scale_row(const int* __restrict__ rowptr, const int* __restrict__ col,
                          const float* __restrict__ dinv, float* __restrict__ val, int n) {
    int i = blockIdx.x * 256 + threadIdx.x;
    if (i < n) {
        int a = rowptr[i], b = rowptr[i + 1];
        float di = dinv[i];
        for (int k = a; k < b; k++) val[k] *= di * dinv[col[k]];
    }
}

// ---------------- MFMA GEMM body (bf16 in, bf16 out), 64 rows/block ----------------
// A: row = lane&15, k = (lane>>4)*8 + kc*32 + j. B from Wt[n][k] bf16.
// D: col = lane&15, row = (lane>>4)*4 + reg. AFP32: A fp32 + cvt (layer 1).
template<int NOUT, bool AFP32>
__device__ __forceinline__ void mgemm_body(int mblk, const void* Ain,
                                           const short* __restrict__ Wt,
                                           short* __restrict__ out, int nrows) {
    constexpr int NT = NOUT / 16;
    int l = threadIdx.x & 63;
    int lr = l & 15;
    int kg = l >> 4;
    int m0 = mblk * 64 + (threadIdx.x >> 6) * 16;
    int arow = m0 + lr;
    bool rowok = arow < nrows;

    bfrag a[4];
    if (AFP32) {
        const float* A = (const float*)Ain + (size_t)arow * 128 + kg * 8;
#pragma unroll
        for (int kc = 0; kc < 4; kc++) {
            bfrag t;
            if (rowok) {
                float4 u0 = *(const float4*)(A + kc * 32);
                float4 u1 = *(const float4*)(A + kc * 32 + 4);
                t[0] = f2bf(u0.x); t[1] = f2bf(u0.y); t[2] = f2bf(u0.z); t[3] = f2bf(u0.w);
                t[4] = f2bf(u1.x); t[5] = f2bf(u1.y); t[6] = f2bf(u1.z); t[7] = f2bf(u1.w);
            } else {
#pragma unroll
                for (int j = 0; j < 8; j++) t[j] = 0;
            }
            a[kc] = t;
        }
    } else {
        const short* A = (const short*)Ain + (size_t)arow * 128 + kg * 8;
#pragma unroll
        for (int kc = 0; kc < 4; kc++) {
            if (rowok) {
                a[kc] = *(const bfrag*)(A + kc * 32);
            } else {
#pragma unroll
                for (int j = 0; j < 8; j++) a[kc][j] = 0;
            }
        }
    }

    f32x4 acc[NT];
#pragma unroll
    for (int t = 0; t < NT; t++)
#pragma unroll
        for (int j = 0; j < 4; j++) acc[t][j] = 0.f;

#pragma unroll
    for (int nt = 0; nt < NT; nt++) {
        const short* Wc = Wt + (size_t)(nt * 16 + lr) * 128 + kg * 8;
#pragma unroll
        for (int kc = 0; kc < 4; kc++) {
            bfrag b = *(const bfrag*)(Wc + kc * 32);
            acc[nt] = __builtin_amdgcn_mfma_f32_16x16x32_bf16(a[kc], b, acc[nt], 0, 0, 0);
        }
    }

#pragma unroll
    for (int nt = 0; nt < NT; nt++) {
#pragma unroll
        for (int r = 0; r < 4; r++) {
            int orow = m0 + kg * 4 + r;
            if (orow >= nrows) continue;
            int ocol = nt * 16 + lr;
            out[(size_t)orow * NOUT + ocol] = f2bf(acc[nt][r]);
        }
    }
}

// ---------------- fused: dst-histogram (256 dedicated blocks) + layer-1 GEMM ----------------
__global__ __launch_bounds__(256) void fused_hist_gemm1(const int* __restrict__ dst,
                                                        int* __restrict__ cnt,
                                                        unsigned short* __restrict__ posr, int e,
                                                        const float* __restrict__ x,
                                                        const short* __restrict__ Wt1,
                                                        short* __restrict__ B, int nrows) {
    if (blockIdx.x < HIST_BLOCKS) {
        const int stride = HIST_BLOCKS * 256;
        int i = blockIdx.x * 256 + threadIdx.x;
        for (; i + 3 * stride < e; i += 4 * stride) {
            int d0 = dst[i];
            int d1 = dst[i + stride];
            int d2 = dst[i + 2 * stride];
            int d3 = dst[i + 3 * stride];
            int p0 = atomicAdd(&cnt[d0], 1);
            int p1 = atomicAdd(&cnt[d1], 1);
            int p2 = atomicAdd(&cnt[d2], 1);
            int p3 = atomicAdd(&cnt[d3], 1);
            posr[i]              = (unsigned short)p0;
            posr[i + stride]     = (unsigned short)p1;
            posr[i + 2 * stride] = (unsigned short)p2;
            posr[i + 3 * stride] = (unsigned short)p3;
        }
        for (; i < e; i += stride) posr[i] = (unsigned short)atomicAdd(&cnt[dst[i]], 1);
        return;
    }
    mgemm_body<128, true>(blockIdx.x - HIST_BLOCKS, x, Wt1, B, nrows);
}

// ---------------- agg row body (F=128, bf16 gathers, x8 unroll) ----------------
__device__ __forceinline__ float2 agg_row128(const unsigned short* __restrict__ h,
                                             const int* __restrict__ col,
                                             const float* __restrict__ val,
                                             int e0, int e1, int lane) {
    const unsigned short* hb = h + 2 * lane;
    float2 a0 = {0.f, 0.f}, a1 = {0.f, 0.f}, a2 = {0.f, 0.f}, a3 = {0.f, 0.f};
    float2 a4 = {0.f, 0.f}, a5 = {0.f, 0.f}, a6 = {0.f, 0.f}, a7 = {0.f, 0.f};
    int e = e0;
    for (; e + 8 <= e1; e += 8) {
        int s0 = col[e+0], s1 = col[e+1], s2 = col[e+2], s3 = col[e+3];
        int s4 = col[e+4], s5 = col[e+5], s6 = col[e+6], s7 = col[e+7];
        float v0 = val[e+0], v1 = val[e+1], v2 = val[e+2], v3 = val[e+3];
        float v4 = val[e+4], v5 = val[e+5], v6 = val[e+6], v7 = val[e+7];
        unsigned u0 = *(const unsigned*)&hb[(size_t)s0 * 128];
        unsigned u1 = *(const unsigned*)&hb[(size_t)s1 * 128];
        unsigned u2 = *(const unsigned*)&hb[(size_t)s2 * 128];
        unsigned u3 = *(const unsigned*)&hb[(size_t)s3 * 128];
        unsigned u4 = *(const unsigned*)&hb[(size_t)s4 * 128];
        unsigned u5 = *(const unsigned*)&hb[(size_t)s5 * 128];
        unsigned u6 = *(const unsigned*)&hb[(size_t)s6 * 128];
        unsigned u7 = *(const unsigned*)&hb[(size_t)s7 * 128];
        a0.x = fmaf(v0, bflo(u0), a0.x); a0.y = fmaf(v0, bfhi(u0), a0.y);
        a1.x = fmaf(v1, bflo(u1), a1.x); a1.y = fmaf(v1, bfhi(u1), a1.y);
        a2.x = fmaf(v2, bflo(u2), a2.x); a2.y = fmaf(v2, bfhi(u2), a2.y);
        a3.x = fmaf(v3, bflo(u3), a3.x); a3.y = fmaf(v3, bfhi(u3), a3.y);
        a4.x = fmaf(v4, bflo(u4), a4.x); a4.y = fmaf(v4, bfhi(u4), a4.y);
        a5.x = fmaf(v5, bflo(u5), a5.x); a5.y = fmaf(v5, bfhi(u5), a5.y);
        a6.x = fmaf(v6, bflo(u6), a6.x); a6.y = fmaf(v6, bfhi(u6), a6.y);
        a7.x = fmaf(v7, bflo(u7), a7.x); a7.y = fmaf(v7, bfhi(u7), a7.y);
    }
    if (e + 4 <= e1) {
        int s0 = col[e+0], s1 = col[e+1], s2 = col[e+2], s3 = col[e+3];
        float v0 = val[e+0], v1 = val[e+1], v2 = val[e+2], v3 = val[e+3];
        unsigned u0 = *(const unsigned*)&hb[(size_t)s0 * 128];
        unsigned u1 = *(const unsigned*)&hb[(size_t)s1 * 128];
        unsigned u2 = *(const unsigned*)&hb[(size_t)s2 * 128];
        unsigned u3 = *(const unsigned*)&hb[(size_t)s3 * 128];
        a0.x = fmaf(v0, bflo(u0), a0.x); a0.y = fmaf(v0, bfhi(u0), a0.y);
        a1.x = fmaf(v1, bflo(u1), a1.x); a1.y = fmaf(v1, bfhi(u1), a1.y);
        a2.x = fmaf(v2, bflo(u2), a2.x); a2.y = fmaf(v2, bfhi(u2), a2.y);
        a3.x = fmaf(v3, bflo(u3), a3.x); a3.y = fmaf(v3, bfhi(u3), a3.y);
        e += 4;
    }
    for (; e < e1; ++e) {
        float v = val[e];
        unsigned u = *(const unsigned*)&hb[(size_t)col[e] * 128];
        a0.x = fmaf(v, bflo(u), a0.x); a0.y = fmaf(v, bfhi(u), a0.y);
    }
    float2 r;
    r.x = ((a0.x + a1.x) + (a2.x + a3.x)) + ((a4.x + a5.x) + (a6.x + a7.x));
    r.y = ((a0.y + a1.y) + (a2.y + a3.y)) + ((a4.y + a5.y) + (a6.y + a7.y));
    return r;
}

// ---------------- fused: agg(+bias+relu) -> next-layer GEMM ----------------
// Block = 256 thr = 4 waves, 16 rows. Agg phase: wave wv computes rows
// wv*4..wv*4+3 into padded LDS [16][136] bf16 (row stride 272B: (row,col)
// bank aliasing only 2-way = free). GEMM phase: each wave MFMAs the 16 rows
// against its NOUT/4-col slice of Wt. out = bf16 [n][NOUT].
template<int NOUT>
__global__ __launch_bounds__(256) void agg_gemm_kernel(const unsigned short* __restrict__ h,
                                                       const int* __restrict__ rowptr,
                                                       const int* __restrict__ col,
                                                       const float* __restrict__ val,
                                                       const float* __restrict__ bias,
                                                       const short* __restrict__ Wt,
                                                       short* __restrict__ out, int n) {
    __shared__ short As[16][136];
    int wv = threadIdx.x >> 6;
    int lane = threadIdx.x & 63;
    int r0 = blockIdx.x * 16;

#pragma unroll
    for (int rr = 0; rr < 4; rr++) {
        int row = r0 + wv * 4 + rr;
        float2 r = {0.f, 0.f};
        if (row < n) {
            int e0 = rowptr[row], e1 = rowptr[row + 1];
            r = agg_row128(h, col, val, e0, e1, lane);
            r.x = fmaxf(r.x + bias[2 * lane + 0], 0.f);
            r.y = fmaxf(r.y + bias[2 * lane + 1], 0.f);
        }
        unsigned pk = (unsigned)(unsigned short)f2bf(r.x)
                    | ((unsigned)(unsigned short)f2bf(r.y) << 16);
        ((unsigned*)&As[wv * 4 + rr][0])[lane] = pk;
    }
    __syncthreads();

    // GEMM: 16 rows x NOUT; wave wv owns cols [wv*NOUT/4, +NOUT/4)
    constexpr int NT = NOUT / 64;            // n-tiles per wave (128->2, 64->1)
    int lr = lane & 15, kg = lane >> 4;
    bfrag a[4];
#pragma unroll
    for (int kc = 0; kc < 4; kc++)
        a[kc] = *(const bfrag*)&As[lr][kg * 8 + kc * 32];

    f32x4 acc[NT];
#pragma unroll
    for (int t = 0; t < NT; t++)
#pragma unroll
        for (int j = 0; j < 4; j++) acc[t][j] = 0.f;

#pragma unroll
    for (int nt = 0; nt < NT; nt++) {
        int ocol = wv * (NOUT / 4) + nt * 16 + lr;
        const short* Wc = Wt + (size_t)ocol * 128 + kg * 8;
#pragma unroll
        for (int kc = 0; kc < 4; kc++) {
            bfrag b = *(const bfrag*)(Wc + kc * 32);
            acc[nt] = __builtin_amdgcn_mfma_f32_16x16x32_bf16(a[kc], b, acc[nt], 0, 0, 0);
        }
    }

#pragma unroll
    for (int nt = 0; nt < NT; nt++) {
        int ocol = wv * (NOUT / 4) + nt * 16 + lr;
#pragma unroll
        for (int r = 0; r < 4; r++) {
            int orow = r0 + kg * 4 + r;
            if (orow < n) out[(size_t)orow * NOUT + ocol] = f2bf(acc[nt][r]);
        }
    }
}

// ---------------- final agg (F=64, bias+sigmoid, fp32 out) ----------------
__global__ __launch_bounds__(256) void agg64_kernel(const unsigned short* __restrict__ h,
                                                    const int* __restrict__ rowptr,
                                                    const int* __restrict__ col,
                                                    const float* __restrict__ val,
                                                    const float* __restrict__ bias,
                                                    float* __restrict__ out, int n) {
    int wv = threadIdx.x >> 6;
    int lane = threadIdx.x & 63;
    int row = blockIdx.x * 4 + wv;
    if (row >= n) return;
    int e0 = rowptr[row], e1 = rowptr[row + 1];
    const unsigned short* hb = h + lane;
    float a0 = 0.f, a1 = 0.f, a2 = 0.f, a3 = 0.f;
    float a4 = 0.f, a5 = 0.f, a6 = 0.f, a7 = 0.f;
    int e = e0;
    for (; e + 8 <= e1; e += 8) {
        int s0 = col[e+0], s1 = col[e+1], s2 = col[e+2], s3 = col[e+3];
        int s4 = col[e+4], s5 = col[e+5], s6 = col[e+6], s7 = col[e+7];
        float v0 = val[e+0], v1 = val[e+1], v2 = val[e+2], v3 = val[e+3];
        float v4 = val[e+4], v5 = val[e+5], v6 = val[e+6], v7 = val[e+7];
        float g0 = bf1(hb[(size_t)s0 * 64]);
        float g1 = bf1(hb[(size_t)s1 * 64]);
        float g2 = bf1(hb[(size_t)s2 * 64]);
        float g3 = bf1(hb[(size_t)s3 * 64]);
        float g4 = bf1(hb[(size_t)s4 * 64]);
        float g5 = bf1(hb[(size_t)s5 * 64]);
        float g6 = bf1(hb[(size_t)s6 * 64]);
        float g7 = bf1(hb[(size_t)s7 * 64]);
        a0 = fmaf(v0, g0, a0); a1 = fmaf(v1, g1, a1);
        a2 = fmaf(v2, g2, a2); a3 = fmaf(v3, g3, a3);
        a4 = fmaf(v4, g4, a4); a5 = fmaf(v5, g5, a5);
        a6 = fmaf(v6, g6, a6); a7 = fmaf(v7, g7, a7);
    }
    if (e + 4 <= e1) {
        int s0 = col[e+0], s1 = col[e+1], s2 = col[e+2], s3 = col[e+3];
        float v0 = val[e+0], v1 = val[e+1], v2 = val[e+2], v3 = val[e+3];
        a0 = fmaf(v0, bf1(hb[(size_t)s0 * 64]), a0);
        a1 = fmaf(v1, bf1(hb[(size_t)s1 * 64]), a1);
        a2 = fmaf(v2, bf1(hb[(size_t)s2 * 64]), a2);
        a3 = fmaf(v3, bf1(hb[(size_t)s3 * 64]), a3);
        e += 4;
    }
    for (; e < e1; ++e) a0 = fmaf(val[e], bf1(hb[(size_t)col[e] * 64]), a0);
    float acc = ((a0 + a1) + (a2 + a3)) + ((a4 + a5) + (a6 + a7));
    acc += bias[lane];
    acc = 1.0f / (1.0f + __expf(-acc));
    out[(size_t)row * 64 + lane] = acc;
}

// ---------------- launch ----------------

extern "C" void kernel_launch(void* const* d_in, const int* in_sizes, int n_in,
                              void* d_out, int out_size, void* d_ws, size_t ws_size,
                              hipStream_t stream) {
    const float* x  = (const float*)d_in[0];
    const int*   ei = (const int*)d_in[1];
    const float* ew = (const float*)d_in[2];
    const float* W1 = (const float*)d_in[3];
    const float* b1 = (const float*)d_in[4];
    const float* W2 = (const float*)d_in[5];
    const float* b2 = (const float*)d_in[6];
    const float* W3 = (const float*)d_in[7];
    const float* b3 = (const float*)d_in[8];
    const float* W4 = (const float*)d_in[9];
    const float* b4 = (const float*)d_in[10];

    const int N = in_sizes[0] / FIN;        // 50000
    const int E = in_sizes[1] / 2;          // 800000
    const int M = N + E;                    // CSR entries incl self-loops
    const int* srcI = ei;                   // edge_index[0]
    const int* dstI = ei + E;               // edge_index[1]

    // carve workspace (256B aligned)
    char* p = (char*)d_ws;
    auto alloc = [&](size_t bytes) -> void* {
        void* r = (void*)p;
        p += (bytes + 255) & ~(size_t)255;
        return r;
    };
    float* dinv   = (float*)alloc((size_t)N * 4);
    int*   cnt    = (int*)  alloc((size_t)N * 4);
    int*   rowptr = (int*)  alloc((size_t)(N + 1) * 4);
    unsigned short* posr = (unsigned short*)alloc((size_t)E * 2);
    int*   col    = (int*)  alloc((size_t)M * 4);
    float* val    = (float*)alloc((size_t)M * 4);
    int*   bsums  = (int*)  alloc(256 * 4);
    short* Ba     = (short*)alloc((size_t)N * 128 * 2);   // ping (bf16)
    short* Bb     = (short*)alloc((size_t)N * 128 * 2);   // pong (bf16)
    short* Wt1    = (short*)alloc(16384 * 2);
    short* Wt2    = (short*)alloc(16384 * 2);
    short* Wt3    = (short*)alloc(16384 * 2);
    short* Wt4    = (short*)alloc(8192 * 2);

    int gN  = (N + 255) / 256;
    int gG  = (N + 63) / 64;
    int gAG = (N + 15) / 16;
    int gA4 = (N + 3) / 4;
    int gM  = (N + E + 255) / 256;
    int nchunks = (N + 1023) / 1024;

    prep_wt<<<224, 256, 0, stream>>>(W1, W2, W3, W4, Wt1, Wt2, Wt3, Wt4, cnt, N);
    // hist (256 dedicated blocks, R9 measured-best) + layer-1 GEMM Ba = x@W1
    fused_hist_gemm1<<<HIST_BLOCKS + gG, 256, 0, stream>>>(dstI, cnt, posr, E,
                                                           x, Wt1, Ba, N);
    scan_chunk<<<nchunks, 256, 0, stream>>>(cnt, rowptr, bsums, N);
    scan_add<<<gN, 256, 0, stream>>>(rowptr, bsums, N, nchunks);
    scatter_csr<<<gM, 256, 0, stream>>>(srcI, dstI, ew, posr, rowptr, col, val, N, E);
    row_dinv<<<gN, 256, 0, stream>>>(rowptr, val, dinv, N);
    scale_row<<<gN, 256, 0, stream>>>(rowptr, col, dinv, val, N);

    // L1 agg(+b1+relu) fused with L2 GEMM: Bb = relu(agg(Ba)+b1) @ W2
    agg_gemm_kernel<128><<<gAG, 256, 0, stream>>>((const unsigned short*)Ba, rowptr, col, val, b1, Wt2, Bb, N);
    // L2 agg fused with L3 GEMM: Ba = relu(agg(Bb)+b2) @ W3
    agg_gemm_kernel<128><<<gAG, 256, 0, stream>>>((const unsigned short*)Bb, rowptr, col, val, b2, Wt3, Ba, N);
    // L3 agg fused with L4 GEMM: Bb = relu(agg(Ba)+b3) @ W4  (64 cols)
    agg_gemm_kernel<64><<<gAG, 256, 0, stream>>>((const unsigned short*)Ba, rowptr, col, val, b3, Wt4, Bb, N);
    // L4 agg + b4 + sigmoid -> out (fp32)
    agg64_kernel<<<gA4, 256, 0, stream>>>((const unsigned short*)Bb, rowptr, col, val, b4, (float*)d_out, N);
}